// Round 3
// baseline (252.227 us; speedup 1.0000x reference)
//
#include <hip/hip_runtime.h>
#include <hip/hip_bf16.h>
#include <math.h>

#define B_  16
#define C_  64
#define H_  128
#define W_  128
#define HW_ (H_ * W_)
#define CR_ 4
#define K9C (9 * C_)   // 576
#define TW  130        // transposed buffer spatial dim (128 + 2 halo)

typedef float f32x4 __attribute__((ext_vector_type(4)));
typedef __bf16 bf16x8 __attribute__((ext_vector_type(8)));

static __device__ __forceinline__ unsigned short f2us(float f) {
    __bf16 h = (__bf16)f;
    return __builtin_bit_cast(unsigned short, h);
}

// ---------------------------------------------------------------------------
// K2: x (NCHW fp32) -> t (b, y', x', c) bf16 with zeroed 1-px halo border.
// Also accumulates per-(b,c) sums into y0 (atomic), replacing a k_mean pass.
__global__ void k_tr(const float* __restrict__ x, unsigned short* __restrict__ t,
                     float* __restrict__ y0) {
    int blk = blockIdx.x;
    int b = blk >> 7, y = blk & 127;
    __shared__ unsigned short lds[C_ * TW];
    int tid = threadIdx.x;
    for (int i = tid; i < C_ * 32; i += 256) {
        int c = i >> 5, xq = i & 31;
        float4 v = *(const float4*)(x + (((size_t)(b * C_ + c)) << 14) + (y << 7) + (xq << 2));
        unsigned int p0 = f2us(v.x) | ((unsigned int)f2us(v.y) << 16);
        unsigned int p1 = f2us(v.z) | ((unsigned int)f2us(v.w) << 16);
        *(unsigned int*)&lds[c * TW + (xq << 2)]     = p0;
        *(unsigned int*)&lds[c * TW + (xq << 2) + 2] = p1;
        float s4 = v.x + v.y + v.z + v.w;
        s4 += __shfl_down(s4, 16, 32);
        s4 += __shfl_down(s4, 8, 32);
        s4 += __shfl_down(s4, 4, 32);
        s4 += __shfl_down(s4, 2, 32);
        s4 += __shfl_down(s4, 1, 32);
        if ((tid & 31) == 0) atomicAdd(&y0[b * C_ + c], s4);
    }
    __syncthreads();
    size_t rowbase = ((size_t)(b * TW + y + 1)) * TW * C_;
    for (int j = tid; j < 128 * 16; j += 256) {
        int px = j >> 4, g = j & 15;
        unsigned short a0 = lds[(4 * g + 0) * TW + px];
        unsigned short a1 = lds[(4 * g + 1) * TW + px];
        unsigned short a2 = lds[(4 * g + 2) * TW + px];
        unsigned short a3 = lds[(4 * g + 3) * TW + px];
        uint2 wv;
        wv.x = a0 | ((unsigned int)a1 << 16);
        wv.y = a2 | ((unsigned int)a3 << 16);
        *(uint2*)(t + rowbase + (size_t)(px + 1) * C_ + (g << 2)) = wv;
    }
    if (tid < 16) {
        int px = (tid < 8) ? 0 : (TW - 1);
        int ch = tid & 7;
        uint4 z = {0, 0, 0, 0};
        *(uint4*)(t + rowbase + (size_t)px * C_ + ch * 8) = z;
    }
    if (y == 0) {
        size_t base = (size_t)b * TW * TW * C_;
        uint4 z = {0, 0, 0, 0};
        for (int i = tid; i < TW * C_ / 8; i += 256)
            *(uint4*)(t + base + (size_t)i * 8) = z;
    }
    if (y == 127) {
        size_t base = ((size_t)(b * TW + TW - 1)) * TW * C_;
        uint4 z = {0, 0, 0, 0};
        for (int i = tid; i < TW * C_ / 8; i += 256)
            *(uint4*)(t + base + (size_t)i * 8) = z;
    }
}

// ---------------------------------------------------------------------------
// K3: transpose se_w1 [16][64][9] -> w1t [tap][o][c] bf16. Also zeroes y0.
__global__ void k_w1t(const float* __restrict__ se_w1, unsigned short* __restrict__ w1t,
                      float* __restrict__ y0) {
    if (blockIdx.x < 4) y0[(blockIdx.x << 8) | threadIdx.x] = 0.f;
    int idx = blockIdx.x * 256 + threadIdx.x;
    int tap = idx >> 10, o = (idx >> 6) & 15, c = idx & 63;
    w1t[idx] = f2us(se_w1[(o * C_ + c) * 9 + tap]);
}

// ---------------------------------------------------------------------------
// K4: fused channel attention + w_t build. Each block (b, mt) redundantly
// computes the tiny FC chain (2.9 KFLOP), then its quarter of the
// MFMA-fragment-ordered w_t. grid = B*4.
__global__ void k_attwt(const float* __restrict__ y0,
                        const float* __restrict__ fc_w1,
                        const float* __restrict__ fc_w2,
                        const float* __restrict__ weight,
                        unsigned short* __restrict__ w_t) {
    int blk = blockIdx.x;
    int b = blk >> 2, mt = blk & 3;
    __shared__ float sy0[C_];
    __shared__ float sh[CR_];
    __shared__ float ssy[K9C];
    __shared__ float sw[16 * 576];
    int tid = threadIdx.x;
    if (tid < C_) sy0[tid] = y0[b * C_ + tid] * (1.0f / (float)HW_);
    const float* wsrc = weight + (size_t)(mt * 16) * 576;
    for (int i = tid; i < 16 * 576; i += 256) sw[i] = wsrc[i];
    __syncthreads();
    if (tid < CR_) {
        float s = 0.f;
        for (int c = 0; c < C_; ++c) s = fmaf(fc_w1[tid * C_ + c], sy0[c], s);
        sh[tid] = fmaxf(s, 0.f);
    }
    __syncthreads();
    for (int i = tid; i < K9C; i += 256) {
        float s = 0.f;
        #pragma unroll
        for (int j = 0; j < CR_; ++j) s = fmaf(fc_w2[i * CR_ + j], sh[j], s);
        ssy[i] = 1.f / (1.f + expf(-s));
    }
    __syncthreads();
    unsigned short* wb = w_t + (size_t)b * 9 * C_ * C_;
    for (int ii = tid; ii < 4608; ii += 256) {
        int i = ii << 1;
        int tap = i >> 10, r = i & 1023;
        int half = r >> 9, lane = (r >> 3) & 63, e = r & 7;
        int o = lane & 15;
        int c = half * 32 + ((lane >> 4) << 3) + e;
        float v0 = sw[o * 576 + c * 9 + tap] * ssy[c * 9 + tap];
        float v1 = sw[o * 576 + (c + 1) * 9 + tap] * ssy[(c + 1) * 9 + tap];
        unsigned int pk = f2us(v0) | ((unsigned int)f2us(v1) << 16);
        *(unsigned int*)(wb + ((tap * 4 + mt) * 2 + half) * 512 + lane * 8 + e) = pk;
    }
}

// ---------------------------------------------------------------------------
// K5: FUSED SE, no x-staging: conv1 B-fragments gather straight from t
// (L1/L2-resident; t's zero halo = conv padding; row/col clamped — clamped
// reads feed only masked-out mid pixels). mid kept fp32 in LDS (25.9 KB,
// 20-float pixel stride -> conflict-free) -> conv2+sigmoid -> A.
// grid = B*64 (16x16 A-tiles), 256 threads.
__global__ void __launch_bounds__(256, 4)
k_se(const unsigned short* __restrict__ t, const unsigned short* __restrict__ w1t,
     const float* __restrict__ se_w2, float* __restrict__ A) {
    int blk = blockIdx.x;
    int b = blk >> 6, tile = blk & 63;
    int ty0 = (tile >> 3) << 4, tx0 = (tile & 7) << 4;
    int tid = threadIdx.x, lane = tid & 63, wave = tid >> 6;
    int n = lane & 15, q = lane >> 4, qc = q << 3;
    __shared__ __align__(16) float ms[324 * 20];   // mid: pixel stride 20 floats
    // 324 mid pixels (18x18, covers A-tile + 1 halo) in 21 groups of 16;
    // group g -> wave g&3 (wave-uniform skip beyond 20).
    int prow[6], pcol[6];
    #pragma unroll
    for (int i = 0; i < 6; ++i) {
        int g = wave + 4 * i;
        int p = g * 16 + n; if (p > 323) p = 323;
        prow[i] = p / 18; pcol[i] = p % 18;
    }
    const unsigned short* tbb = t + (size_t)b * TW * TW * C_;
    f32x4 acc[6] = {};
    #pragma unroll
    for (int tap = 0; tap < 9; ++tap) {
        int ki = tap / 3, kj = tap % 3;
        uint4 a0 = *(const uint4*)(w1t + (tap * 16 + n) * C_ + qc);
        uint4 a1 = *(const uint4*)(w1t + (tap * 16 + n) * C_ + 32 + qc);
        bf16x8 af0 = __builtin_bit_cast(bf16x8, a0);
        bf16x8 af1 = __builtin_bit_cast(bf16x8, a1);
        #pragma unroll
        for (int i = 0; i < 6; ++i) {
            int g = wave + 4 * i;
            if (g < 21) {
                int tr = ty0 - 1 + prow[i] + ki;
                tr = tr < 0 ? 0 : (tr > TW - 1 ? TW - 1 : tr);
                int tc = tx0 - 1 + pcol[i] + kj;
                tc = tc < 0 ? 0 : (tc > TW - 1 ? TW - 1 : tc);
                const unsigned short* px = tbb + ((size_t)tr * TW + tc) * C_;
                bf16x8 b0 = *(const bf16x8*)(px + qc);
                bf16x8 b1 = *(const bf16x8*)(px + 32 + qc);
                acc[i] = __builtin_amdgcn_mfma_f32_16x16x32_bf16(af0, b0, acc[i], 0, 0, 0);
                acc[i] = __builtin_amdgcn_mfma_f32_16x16x32_bf16(af1, b1, acc[i], 0, 0, 0);
            }
        }
    }
    // relu + border mask -> fp32 mid in LDS
    #pragma unroll
    for (int i = 0; i < 6; ++i) {
        int g = wave + 4 * i;
        int p = g * 16 + n;
        if (g < 21 && p < 324) {
            int my = ty0 - 1 + prow[i], mx = tx0 - 1 + pcol[i];
            bool valid = (my >= 0) && (my < 128) && (mx >= 0) && (mx < 128);
            f32x4 v;
            v[0] = valid ? fmaxf(acc[i][0], 0.f) : 0.f;
            v[1] = valid ? fmaxf(acc[i][1], 0.f) : 0.f;
            v[2] = valid ? fmaxf(acc[i][2], 0.f) : 0.f;
            v[3] = valid ? fmaxf(acc[i][3], 0.f) : 0.f;
            *(f32x4*)&ms[p * 20 + (q << 2)] = v;
        }
    }
    __syncthreads();
    // conv2 + sigmoid: one thread per A-pixel, fp32 reads, no converts
    int arow = tid >> 4, acol = tid & 15;
    float s = 0.f;
    #pragma unroll
    for (int di = 0; di < 3; ++di) {
        #pragma unroll
        for (int dj = 0; dj < 3; ++dj) {
            const float* pp = &ms[((arow + di) * 18 + acol + dj) * 20];
            #pragma unroll
            for (int c = 0; c < 16; ++c)
                s = fmaf(pp[c], se_w2[c * 9 + di * 3 + dj], s);
        }
    }
    A[(b << 14) + ((ty0 + arow) << 7) + tx0 + acol] = 1.f / (1.f + expf(-s));
}

// ---------------------------------------------------------------------------
// K7: main conv via MFMA. 8x32 px tile, 256 threads (4 waves = 2wy x 2wx),
// launch_bounds(256,3) -> 170-reg cap, no spill. LDS 43520 B swizzled ->
// 3 blocks/CU. Epilogue transposes through LDS -> full-line dwordx4 stores.
__global__ void __launch_bounds__(256, 3)
k_main(const unsigned short* __restrict__ t, const unsigned short* __restrict__ w_t,
       const float* __restrict__ A, float* __restrict__ out) {
    int blk = blockIdx.x;
    int b = blk >> 6, tile = blk & 63;
    int ty0 = (tile >> 2) << 3, tx0 = (tile & 3) << 5;
    int tid = threadIdx.x, lane = tid & 63, wave = tid >> 6;
    int wy = wave >> 1, wx = wave & 1;
    int n = lane & 15, q = lane >> 4;
    __shared__ __align__(16) char smem[10 * 34 * 128];   // 43520 B
    float* fb = (float*)smem;                            // epilogue reuse [128][32]
    const unsigned short* tb = t + ((size_t)b * TW + ty0) * TW * C_ + (size_t)tx0 * C_;
    for (int i = tid; i < 10 * 34 * 8; i += 256) {
        int row = i / 272, r = i % 272, px = r >> 3, ch = r & 7;
        uint4 v = *(const uint4*)(tb + ((size_t)row * TW + px) * C_ + ch * 8);
        *(uint4*)(smem + (row * 34 + px) * 128 + ((ch ^ (px & 7)) << 4)) = v;
    }
    __syncthreads();
    f32x4 acc[4][4] = {};   // [m-tile][row j]
    const unsigned short* wb = w_t + (size_t)b * 9 * C_ * C_;
    #pragma unroll
    for (int tap = 0; tap < 9; ++tap) {
        int ki = tap / 3, kj = tap % 3;
        int xl = (wx << 4) + n + kj;
        int xk = xl & 7;
        #pragma unroll
        for (int half = 0; half < 2; ++half) {
            bf16x8 af[4];
            #pragma unroll
            for (int mt = 0; mt < 4; ++mt) {
                uint4 au = *(const uint4*)(wb + (((tap * 4 + mt) * 2 + half) << 9) + (lane << 3));
                af[mt] = __builtin_bit_cast(bf16x8, au);
            }
            int slot = (((half << 2) + q) ^ xk) << 4;
            #pragma unroll
            for (int j = 0; j < 4; ++j) {
                int yl = (wy << 2) + j + ki;
                bf16x8 bf = *(const bf16x8*)(smem + (yl * 34 + xl) * 128 + slot);
                #pragma unroll
                for (int mt = 0; mt < 4; ++mt)
                    acc[mt][j] = __builtin_amdgcn_mfma_f32_16x16x32_bf16(af[mt], bf, acc[mt][j], 0, 0, 0);
            }
        }
    }
    // epilogue: per j-row, A-scale -> LDS transpose -> full-line dwordx4 stores
    int xx = tx0 + (wx << 4) + n;
    #pragma unroll
    for (int j = 0; j < 4; ++j) {
        __syncthreads();   // j=0: xt reads done; j>0: prev readback done
        int y = ty0 + (wy << 2) + j;
        float a = A[(b << 14) + (y << 7) + xx];
        #pragma unroll
        for (int mt = 0; mt < 4; ++mt) {
            #pragma unroll
            for (int r = 0; r < 4; ++r) {
                int o = (mt << 4) + (q << 2) + r;
                fb[(((wy << 6) + o) << 5) + (wx << 4) + n] = acc[mt][j][r] * a;
            }
        }
        __syncthreads();
        #pragma unroll
        for (int it = 0; it < 4; ++it) {
            int s = it * 256 + tid;
            int row = s >> 3, xq = s & 7;
            int wy2 = row >> 6, o = row & 63;
            float4 v = *(const float4*)&fb[(row << 5) + (xq << 2)];
            *(float4*)(out + (((size_t)(b * C_ + o)) << 14) +
                       ((ty0 + (wy2 << 2) + j) << 7) + tx0 + (xq << 2)) = v;
        }
    }
}

// ---------------------------------------------------------------------------
extern "C" void kernel_launch(void* const* d_in, const int* in_sizes, int n_in,
                              void* d_out, int out_size, void* d_ws, size_t ws_size,
                              hipStream_t stream) {
    const float* x      = (const float*)d_in[0];
    const float* weight = (const float*)d_in[1];
    const float* se_w1  = (const float*)d_in[2];
    const float* se_w2  = (const float*)d_in[3];
    const float* fc_w1  = (const float*)d_in[4];
    const float* fc_w2  = (const float*)d_in[5];
    float* out = (float*)d_out;

    char* ws = (char*)d_ws;
    float* y0            = (float*)ws;                         ws += 4096;
    float* A             = (float*)ws;                         ws += (size_t)B_ * HW_ * 4;
    unsigned short* t    = (unsigned short*)ws;                ws += (size_t)B_ * TW * TW * C_ * 2 + 4096;
    unsigned short* w_t  = (unsigned short*)ws;                ws += (size_t)B_ * 9 * C_ * C_ * 2;
    unsigned short* w1t  = (unsigned short*)ws;

    k_w1t  <<<36, 256, 0, stream>>>(se_w1, w1t, y0);          // zeroes y0 first
    k_tr   <<<B_ * H_, 256, 0, stream>>>(x, t, y0);           // + fused mean
    k_attwt<<<B_ * 4, 256, 0, stream>>>(y0, fc_w1, fc_w2, weight, w_t);
    k_se   <<<B_ * 64, 256, 0, stream>>>(t, w1t, se_w2, A);
    k_main <<<B_ * 64, 256, 0, stream>>>(t, w_t, A, out);
}

// Round 4
// 244.152 us; speedup vs baseline: 1.0331x; 1.0331x over previous
//
#include <hip/hip_runtime.h>
#include <hip/hip_bf16.h>
#include <math.h>

#define B_  16
#define C_  64
#define H_  128
#define W_  128
#define HW_ (H_ * W_)
#define CR_ 4
#define K9C (9 * C_)   // 576
#define TW  130        // transposed buffer spatial dim (128 + 2 halo)
#define FBS 36         // k_main epilogue fb row stride (floats)

typedef float f32x4 __attribute__((ext_vector_type(4)));
typedef __bf16 bf16x8 __attribute__((ext_vector_type(8)));

static __device__ __forceinline__ unsigned short f2us(float f) {
    __bf16 h = (__bf16)f;
    return __builtin_bit_cast(unsigned short, h);
}

// XCD-aware bijective swizzles: dispatch is round-robin over 8 XCDs; remap so
// each XCD walks one batch's tiles at a time (per-XCD L2 working set = one
// batch's t = 2.16 MB < 4 MB L2).
static __device__ __forceinline__ int swz64(int blk) {   // grid 1024, 64 tiles/b
    int xcd = blk & 7, i = blk >> 3;
    return ((i >> 6) << 9) + (xcd << 6) + (i & 63);
}
static __device__ __forceinline__ int swz128(int blk) {  // grid 2048, 128 tiles/b
    int xcd = blk & 7, i = blk >> 3;
    return ((i >> 7) << 10) + (xcd << 7) + (i & 127);
}

// ---------------------------------------------------------------------------
// K2: x (NCHW fp32) -> t (b, y', x', c) bf16 with zeroed 1-px halo border.
// Also accumulates per-(b,c) sums into y0 (atomic), replacing a k_mean pass.
__global__ void k_tr(const float* __restrict__ x, unsigned short* __restrict__ t,
                     float* __restrict__ y0) {
    int blk = blockIdx.x;
    int b = blk >> 7, y = blk & 127;
    __shared__ unsigned short lds[C_ * TW];
    int tid = threadIdx.x;
    for (int i = tid; i < C_ * 32; i += 256) {
        int c = i >> 5, xq = i & 31;
        float4 v = *(const float4*)(x + (((size_t)(b * C_ + c)) << 14) + (y << 7) + (xq << 2));
        unsigned int p0 = f2us(v.x) | ((unsigned int)f2us(v.y) << 16);
        unsigned int p1 = f2us(v.z) | ((unsigned int)f2us(v.w) << 16);
        *(unsigned int*)&lds[c * TW + (xq << 2)]     = p0;
        *(unsigned int*)&lds[c * TW + (xq << 2) + 2] = p1;
        float s4 = v.x + v.y + v.z + v.w;
        s4 += __shfl_down(s4, 16, 32);
        s4 += __shfl_down(s4, 8, 32);
        s4 += __shfl_down(s4, 4, 32);
        s4 += __shfl_down(s4, 2, 32);
        s4 += __shfl_down(s4, 1, 32);
        if ((tid & 31) == 0) atomicAdd(&y0[b * C_ + c], s4);
    }
    __syncthreads();
    size_t rowbase = ((size_t)(b * TW + y + 1)) * TW * C_;
    for (int j = tid; j < 128 * 16; j += 256) {
        int px = j >> 4, g = j & 15;
        unsigned short a0 = lds[(4 * g + 0) * TW + px];
        unsigned short a1 = lds[(4 * g + 1) * TW + px];
        unsigned short a2 = lds[(4 * g + 2) * TW + px];
        unsigned short a3 = lds[(4 * g + 3) * TW + px];
        uint2 wv;
        wv.x = a0 | ((unsigned int)a1 << 16);
        wv.y = a2 | ((unsigned int)a3 << 16);
        *(uint2*)(t + rowbase + (size_t)(px + 1) * C_ + (g << 2)) = wv;
    }
    if (tid < 16) {
        int px = (tid < 8) ? 0 : (TW - 1);
        int ch = tid & 7;
        uint4 z = {0, 0, 0, 0};
        *(uint4*)(t + rowbase + (size_t)px * C_ + ch * 8) = z;
    }
    if (y == 0) {
        size_t base = (size_t)b * TW * TW * C_;
        uint4 z = {0, 0, 0, 0};
        for (int i = tid; i < TW * C_ / 8; i += 256)
            *(uint4*)(t + base + (size_t)i * 8) = z;
    }
    if (y == 127) {
        size_t base = ((size_t)(b * TW + TW - 1)) * TW * C_;
        uint4 z = {0, 0, 0, 0};
        for (int i = tid; i < TW * C_ / 8; i += 256)
            *(uint4*)(t + base + (size_t)i * 8) = z;
    }
}

// ---------------------------------------------------------------------------
// K3: transpose se_w1 [16][64][9] -> w1t [tap][o][c] bf16. Also zeroes y0.
__global__ void k_w1t(const float* __restrict__ se_w1, unsigned short* __restrict__ w1t,
                      float* __restrict__ y0) {
    if (blockIdx.x < 4) y0[(blockIdx.x << 8) | threadIdx.x] = 0.f;
    int idx = blockIdx.x * 256 + threadIdx.x;
    int tap = idx >> 10, o = (idx >> 6) & 15, c = idx & 63;
    w1t[idx] = f2us(se_w1[(o * C_ + c) * 9 + tap]);
}

// ---------------------------------------------------------------------------
// K4: fused channel attention + w_t build (fragment-ordered). grid = B*4.
__global__ void k_attwt(const float* __restrict__ y0,
                        const float* __restrict__ fc_w1,
                        const float* __restrict__ fc_w2,
                        const float* __restrict__ weight,
                        unsigned short* __restrict__ w_t) {
    int blk = blockIdx.x;
    int b = blk >> 2, mt = blk & 3;
    __shared__ float sy0[C_];
    __shared__ float sh[CR_];
    __shared__ float ssy[K9C];
    __shared__ float sw[16 * 576];
    int tid = threadIdx.x;
    if (tid < C_) sy0[tid] = y0[b * C_ + tid] * (1.0f / (float)HW_);
    const float* wsrc = weight + (size_t)(mt * 16) * 576;
    for (int i = tid; i < 16 * 576; i += 256) sw[i] = wsrc[i];
    __syncthreads();
    if (tid < CR_) {
        float s = 0.f;
        for (int c = 0; c < C_; ++c) s = fmaf(fc_w1[tid * C_ + c], sy0[c], s);
        sh[tid] = fmaxf(s, 0.f);
    }
    __syncthreads();
    for (int i = tid; i < K9C; i += 256) {
        float s = 0.f;
        #pragma unroll
        for (int j = 0; j < CR_; ++j) s = fmaf(fc_w2[i * CR_ + j], sh[j], s);
        ssy[i] = 1.f / (1.f + expf(-s));
    }
    __syncthreads();
    unsigned short* wb = w_t + (size_t)b * 9 * C_ * C_;
    for (int ii = tid; ii < 4608; ii += 256) {
        int i = ii << 1;
        int tap = i >> 10, r = i & 1023;
        int half = r >> 9, lane = (r >> 3) & 63, e = r & 7;
        int o = lane & 15;
        int c = half * 32 + ((lane >> 4) << 3) + e;
        float v0 = sw[o * 576 + c * 9 + tap] * ssy[c * 9 + tap];
        float v1 = sw[o * 576 + (c + 1) * 9 + tap] * ssy[(c + 1) * 9 + tap];
        unsigned int pk = f2us(v0) | ((unsigned int)f2us(v1) << 16);
        *(unsigned int*)(wb + ((tap * 4 + mt) * 2 + half) * 512 + lane * 8 + e) = pk;
    }
}

// ---------------------------------------------------------------------------
// K5: FUSED SE, 8x16 A-tiles (grid 2048, XCD-swizzled), direct gather from t.
// Clamp-free addressing: t has 2 guard rows before/after, so out-of-range
// taps read mapped garbage that only feeds border-masked mid pixels.
// mid fp32 in LDS (180 px * 20-float stride = 14.4 KB). launch_bounds(256,6)
// -> 6 blocks/CU resident = 75% occupancy.
__global__ void __launch_bounds__(256, 6)
k_se(const unsigned short* __restrict__ t, const unsigned short* __restrict__ w1t,
     const float* __restrict__ se_w2, float* __restrict__ A) {
    int blk = swz128(blockIdx.x);
    int b = blk >> 7, tile = blk & 127;
    int ty0 = (tile >> 3) << 3, tx0 = (tile & 7) << 4;
    int tid = threadIdx.x, lane = tid & 63, wave = tid >> 6;
    int n = lane & 15, q = lane >> 4, qc = q << 3;
    __shared__ __align__(16) float ms[180 * 20];
    // 180 mid pixels (10x18: 8x16 A-tile + 1 halo) in 12 groups of 16;
    // group g = wave + 4*i.
    int prow[3], pcol[3];
    long base[3];
    #pragma unroll
    for (int i = 0; i < 3; ++i) {
        int g = wave + 4 * i;
        int p = g * 16 + n; if (p > 179) p = 179;
        prow[i] = p / 18; pcol[i] = p % 18;
        base[i] = ((long)(ty0 - 1 + prow[i]) * TW + (tx0 - 1 + pcol[i])) * C_;
    }
    const unsigned short* tbb = t + (size_t)b * TW * TW * C_;
    f32x4 acc[3] = {};
    #pragma unroll
    for (int tap = 0; tap < 9; ++tap) {
        int ki = tap / 3, kj = tap % 3;
        long toff = (long)(ki * TW + kj) * C_;
        uint4 a0 = *(const uint4*)(w1t + (tap * 16 + n) * C_ + qc);
        uint4 a1 = *(const uint4*)(w1t + (tap * 16 + n) * C_ + 32 + qc);
        bf16x8 af0 = __builtin_bit_cast(bf16x8, a0);
        bf16x8 af1 = __builtin_bit_cast(bf16x8, a1);
        #pragma unroll
        for (int i = 0; i < 3; ++i) {
            const unsigned short* px = tbb + base[i] + toff;
            bf16x8 b0 = *(const bf16x8*)(px + qc);
            bf16x8 b1 = *(const bf16x8*)(px + 32 + qc);
            acc[i] = __builtin_amdgcn_mfma_f32_16x16x32_bf16(af0, b0, acc[i], 0, 0, 0);
            acc[i] = __builtin_amdgcn_mfma_f32_16x16x32_bf16(af1, b1, acc[i], 0, 0, 0);
        }
    }
    // relu + border mask -> fp32 mid in LDS
    #pragma unroll
    for (int i = 0; i < 3; ++i) {
        int g = wave + 4 * i;
        int p = g * 16 + n;
        if (p < 180) {
            int my = ty0 - 1 + prow[i], mx = tx0 - 1 + pcol[i];
            bool valid = (my >= 0) && (my < 128) && (mx >= 0) && (mx < 128);
            f32x4 v;
            v[0] = valid ? fmaxf(acc[i][0], 0.f) : 0.f;
            v[1] = valid ? fmaxf(acc[i][1], 0.f) : 0.f;
            v[2] = valid ? fmaxf(acc[i][2], 0.f) : 0.f;
            v[3] = valid ? fmaxf(acc[i][3], 0.f) : 0.f;
            *(f32x4*)&ms[p * 20 + (q << 2)] = v;
        }
    }
    __syncthreads();
    // conv2 + sigmoid: one thread per A-pixel (128 of 256 active)
    if (tid < 128) {
        int arow = tid >> 4, acol = tid & 15;
        float s = 0.f;
        #pragma unroll
        for (int di = 0; di < 3; ++di) {
            #pragma unroll
            for (int dj = 0; dj < 3; ++dj) {
                const float* pp = &ms[((arow + di) * 18 + acol + dj) * 20];
                #pragma unroll
                for (int c = 0; c < 16; ++c)
                    s = fmaf(pp[c], se_w2[c * 9 + di * 3 + dj], s);
            }
        }
        A[(b << 14) + ((ty0 + arow) << 7) + tx0 + acol] = 1.f / (1.f + expf(-s));
    }
}

// ---------------------------------------------------------------------------
// K7: main conv via MFMA. 8x32 px tile, 512 threads (8 waves = 4wy x 2wx),
// acc[4][2] = 32 VGPR/thread -> fits launch_bounds(512,4)'s 128-reg cap
// (round-1 spill was acc=64 needing 148). 2 blocks/CU = 16 waves/CU.
// XCD-swizzled. LDS 43520 B swizzled staging; epilogue via LDS transpose
// (stride FBS=36: 2-way write banks, aligned float4 readback) -> full-line
// dwordx4 stores.
__global__ void __launch_bounds__(512, 4)
k_main(const unsigned short* __restrict__ t, const unsigned short* __restrict__ w_t,
       const float* __restrict__ A, float* __restrict__ out) {
    int blk = swz64(blockIdx.x);
    int b = blk >> 6, tile = blk & 63;
    int ty0 = (tile >> 2) << 3, tx0 = (tile & 3) << 5;
    int tid = threadIdx.x, lane = tid & 63, wave = tid >> 6;
    int wy = wave >> 1, wx = wave & 1;
    int n = lane & 15, q = lane >> 4;
    __shared__ __align__(16) char smem[10 * 34 * 128];   // 43520 B
    float* fb = (float*)smem;                            // epilogue reuse [256][FBS]
    const unsigned short* tb = t + ((size_t)b * TW + ty0) * TW * C_ + (size_t)tx0 * C_;
    for (int i = tid; i < 10 * 34 * 8; i += 512) {
        int row = i / 272, r = i % 272, px = r >> 3, ch = r & 7;
        uint4 v = *(const uint4*)(tb + ((size_t)row * TW + px) * C_ + ch * 8);
        *(uint4*)(smem + (row * 34 + px) * 128 + ((ch ^ (px & 7)) << 4)) = v;
    }
    __syncthreads();
    f32x4 acc[4][2] = {};   // [m-tile][row j2]
    const unsigned short* wb = w_t + (size_t)b * 9 * C_ * C_;
    #pragma unroll
    for (int tap = 0; tap < 9; ++tap) {
        int ki = tap / 3, kj = tap % 3;
        int xl = (wx << 4) + n + kj;
        int xk = xl & 7;
        #pragma unroll
        for (int half = 0; half < 2; ++half) {
            bf16x8 af[4];
            #pragma unroll
            for (int mt = 0; mt < 4; ++mt) {
                uint4 au = *(const uint4*)(wb + (((tap * 4 + mt) * 2 + half) << 9) + (lane << 3));
                af[mt] = __builtin_bit_cast(bf16x8, au);
            }
            int slot = (((half << 2) + q) ^ xk) << 4;
            #pragma unroll
            for (int j2 = 0; j2 < 2; ++j2) {
                int yl = (wy << 1) + j2 + ki;
                bf16x8 bf = *(const bf16x8*)(smem + (yl * 34 + xl) * 128 + slot);
                #pragma unroll
                for (int mt = 0; mt < 4; ++mt)
                    acc[mt][j2] = __builtin_amdgcn_mfma_f32_16x16x32_bf16(af[mt], bf, acc[mt][j2], 0, 0, 0);
            }
        }
    }
    // epilogue: 2 phases; A-scale -> LDS transpose -> full-line dwordx4 stores
    int xx = tx0 + (wx << 4) + n;
    #pragma unroll
    for (int j2 = 0; j2 < 2; ++j2) {
        __syncthreads();   // j2=0: staging reads done; j2=1: prev readback done
        int y = ty0 + (wy << 1) + j2;
        float a = A[(b << 14) + (y << 7) + xx];
        #pragma unroll
        for (int mt = 0; mt < 4; ++mt) {
            #pragma unroll
            for (int r = 0; r < 4; ++r) {
                int o = (mt << 4) + (q << 2) + r;
                fb[((wy << 6) + o) * FBS + (wx << 4) + n] = acc[mt][j2][r] * a;
            }
        }
        __syncthreads();
        #pragma unroll
        for (int it = 0; it < 4; ++it) {
            int s = it * 512 + tid;
            int row = s >> 3, xq = s & 7;
            int wy2 = row >> 6, o = row & 63;
            float4 v = *(const float4*)&fb[row * FBS + (xq << 2)];
            *(float4*)(out + (((size_t)(b * C_ + o)) << 14) +
                       ((ty0 + (wy2 << 1) + j2) << 7) + tx0 + (xq << 2)) = v;
        }
    }
}

// ---------------------------------------------------------------------------
extern "C" void kernel_launch(void* const* d_in, const int* in_sizes, int n_in,
                              void* d_out, int out_size, void* d_ws, size_t ws_size,
                              hipStream_t stream) {
    const float* x      = (const float*)d_in[0];
    const float* weight = (const float*)d_in[1];
    const float* se_w1  = (const float*)d_in[2];
    const float* se_w2  = (const float*)d_in[3];
    const float* fc_w1  = (const float*)d_in[4];
    const float* fc_w2  = (const float*)d_in[5];
    float* out = (float*)d_out;

    char* ws = (char*)d_ws;
    float* y0            = (float*)ws;                         ws += 4096;
    float* A             = (float*)ws;                         ws += (size_t)B_ * HW_ * 4;
    ws += 2 * TW * C_ * 2;                                     // front guard rows
    unsigned short* t    = (unsigned short*)ws;                ws += (size_t)B_ * TW * TW * C_ * 2;
    ws += 2 * TW * C_ * 2 + 4096;                              // back guard rows
    unsigned short* w_t  = (unsigned short*)ws;                ws += (size_t)B_ * 9 * C_ * C_ * 2;
    unsigned short* w1t  = (unsigned short*)ws;

    k_w1t  <<<36, 256, 0, stream>>>(se_w1, w1t, y0);          // zeroes y0 first
    k_tr   <<<B_ * H_, 256, 0, stream>>>(x, t, y0);           // + fused mean
    k_attwt<<<B_ * 4, 256, 0, stream>>>(y0, fc_w1, fc_w2, weight, w_t);
    k_se   <<<B_ * 128, 256, 0, stream>>>(t, w1t, se_w2, A);
    k_main <<<B_ * 64, 512, 0, stream>>>(t, w_t, A, out);
}

// Round 5
// 218.767 us; speedup vs baseline: 1.1529x; 1.1160x over previous
//
#include <hip/hip_runtime.h>
#include <hip/hip_bf16.h>
#include <math.h>

#define B_  16
#define C_  64
#define H_  128
#define W_  128
#define HW_ (H_ * W_)
#define CR_ 4
#define K9C (9 * C_)   // 576
#define TW  130        // transposed buffer spatial dim (128 + 2 halo)
#define FBS 36         // epilogue fb row stride (floats)
#define STG_W 36       // staged tile: 12 rows x 36 cols of pixels (128B each)
#define STG_H 12
#define MIDOFF (STG_H * STG_W * 128)        // 55296
#define MIDS 18                             // mid pixel stride (floats)
#define W2OFF (MIDOFF + 340 * MIDS * 4)     // 55296 + 24480 = 79776
#define LDSZ  (W2OFF + 144 * 4)             // 80352 (<= 81920: 2 blocks/CU)

typedef float f32x4 __attribute__((ext_vector_type(4)));
typedef __bf16 bf16x8 __attribute__((ext_vector_type(8)));

static __device__ __forceinline__ unsigned short f2us(float f) {
    __bf16 h = (__bf16)f;
    return __builtin_bit_cast(unsigned short, h);
}

// XCD-aware bijective swizzle: grid 1024 = 16 batches x 64 tiles; each XCD
// walks whole batches (per-XCD L2 working set = one batch's t = 2.16 MB).
static __device__ __forceinline__ int swz64(int blk) {
    int xcd = blk & 7, i = blk >> 3;
    return ((i >> 6) << 9) + (xcd << 6) + (i & 63);
}

// ---------------------------------------------------------------------------
// K2: x (NCHW fp32) -> t (b, y', x', c) bf16 with zeroed 1-px halo border.
// Also accumulates per-(b,c) sums into y0 (atomic), fused mean.
__global__ void k_tr(const float* __restrict__ x, unsigned short* __restrict__ t,
                     float* __restrict__ y0) {
    int blk = blockIdx.x;
    int b = blk >> 7, y = blk & 127;
    __shared__ unsigned short lds[C_ * TW];
    int tid = threadIdx.x;
    for (int i = tid; i < C_ * 32; i += 256) {
        int c = i >> 5, xq = i & 31;
        float4 v = *(const float4*)(x + (((size_t)(b * C_ + c)) << 14) + (y << 7) + (xq << 2));
        unsigned int p0 = f2us(v.x) | ((unsigned int)f2us(v.y) << 16);
        unsigned int p1 = f2us(v.z) | ((unsigned int)f2us(v.w) << 16);
        *(unsigned int*)&lds[c * TW + (xq << 2)]     = p0;
        *(unsigned int*)&lds[c * TW + (xq << 2) + 2] = p1;
        float s4 = v.x + v.y + v.z + v.w;
        s4 += __shfl_down(s4, 16, 32);
        s4 += __shfl_down(s4, 8, 32);
        s4 += __shfl_down(s4, 4, 32);
        s4 += __shfl_down(s4, 2, 32);
        s4 += __shfl_down(s4, 1, 32);
        if ((tid & 31) == 0) atomicAdd(&y0[b * C_ + c], s4);
    }
    __syncthreads();
    size_t rowbase = ((size_t)(b * TW + y + 1)) * TW * C_;
    for (int j = tid; j < 128 * 16; j += 256) {
        int px = j >> 4, g = j & 15;
        unsigned short a0 = lds[(4 * g + 0) * TW + px];
        unsigned short a1 = lds[(4 * g + 1) * TW + px];
        unsigned short a2 = lds[(4 * g + 2) * TW + px];
        unsigned short a3 = lds[(4 * g + 3) * TW + px];
        uint2 wv;
        wv.x = a0 | ((unsigned int)a1 << 16);
        wv.y = a2 | ((unsigned int)a3 << 16);
        *(uint2*)(t + rowbase + (size_t)(px + 1) * C_ + (g << 2)) = wv;
    }
    if (tid < 16) {
        int px = (tid < 8) ? 0 : (TW - 1);
        int ch = tid & 7;
        uint4 z = {0, 0, 0, 0};
        *(uint4*)(t + rowbase + (size_t)px * C_ + ch * 8) = z;
    }
    if (y == 0) {
        size_t base = (size_t)b * TW * TW * C_;
        uint4 z = {0, 0, 0, 0};
        for (int i = tid; i < TW * C_ / 8; i += 256)
            *(uint4*)(t + base + (size_t)i * 8) = z;
    }
    if (y == 127) {
        size_t base = ((size_t)(b * TW + TW - 1)) * TW * C_;
        uint4 z = {0, 0, 0, 0};
        for (int i = tid; i < TW * C_ / 8; i += 256)
            *(uint4*)(t + base + (size_t)i * 8) = z;
    }
}

// ---------------------------------------------------------------------------
// K3: transpose se_w1 [16][64][9] -> w1t [tap][o][c] bf16. Also zeroes y0.
__global__ void k_w1t(const float* __restrict__ se_w1, unsigned short* __restrict__ w1t,
                      float* __restrict__ y0) {
    if (blockIdx.x < 4) y0[(blockIdx.x << 8) | threadIdx.x] = 0.f;
    int idx = blockIdx.x * 256 + threadIdx.x;
    int tap = idx >> 10, o = (idx >> 6) & 15, c = idx & 63;
    w1t[idx] = f2us(se_w1[(o * C_ + c) * 9 + tap]);
}

// ---------------------------------------------------------------------------
// K4: fused channel attention + w_t build (MFMA-fragment-ordered). grid = B*4.
__global__ void k_attwt(const float* __restrict__ y0,
                        const float* __restrict__ fc_w1,
                        const float* __restrict__ fc_w2,
                        const float* __restrict__ weight,
                        unsigned short* __restrict__ w_t) {
    int blk = blockIdx.x;
    int b = blk >> 2, mt = blk & 3;
    __shared__ float sy0[C_];
    __shared__ float sh[CR_];
    __shared__ float ssy[K9C];
    __shared__ float sw[16 * 576];
    int tid = threadIdx.x;
    if (tid < C_) sy0[tid] = y0[b * C_ + tid] * (1.0f / (float)HW_);
    const float* wsrc = weight + (size_t)(mt * 16) * 576;
    for (int i = tid; i < 16 * 576; i += 256) sw[i] = wsrc[i];
    __syncthreads();
    if (tid < CR_) {
        float s = 0.f;
        for (int c = 0; c < C_; ++c) s = fmaf(fc_w1[tid * C_ + c], sy0[c], s);
        sh[tid] = fmaxf(s, 0.f);
    }
    __syncthreads();
    for (int i = tid; i < K9C; i += 256) {
        float s = 0.f;
        #pragma unroll
        for (int j = 0; j < CR_; ++j) s = fmaf(fc_w2[i * CR_ + j], sh[j], s);
        ssy[i] = 1.f / (1.f + expf(-s));
    }
    __syncthreads();
    unsigned short* wb = w_t + (size_t)b * 9 * C_ * C_;
    for (int ii = tid; ii < 4608; ii += 256) {
        int i = ii << 1;
        int tap = i >> 10, r = i & 1023;
        int half = r >> 9, lane = (r >> 3) & 63, e = r & 7;
        int o = lane & 15;
        int c = half * 32 + ((lane >> 4) << 3) + e;
        float v0 = sw[o * 576 + c * 9 + tap] * ssy[c * 9 + tap];
        float v1 = sw[o * 576 + (c + 1) * 9 + tap] * ssy[(c + 1) * 9 + tap];
        unsigned int pk = f2us(v0) | ((unsigned int)f2us(v1) << 16);
        *(unsigned int*)(wb + ((tap * 4 + mt) * 2 + half) * 512 + lane * 8 + e) = pk;
    }
}

// ---------------------------------------------------------------------------
// K5: FULLY FUSED main+SE. 8x32 output tile, 512 threads (8 waves = 4wy x 2wx).
// Stage 12x36 t-pixels (clamped; covers main conv AND conv1 halo) -> LDS.
// conv1 (22 MFMA-groups over 340 mid px) -> mid fp32 in LDS (border-masked),
// main conv (1152 MFMA), barrier, conv2+sigmoid in registers (q-split chans
// + shfl reduce) -> A in regs, epilogue A-scale -> LDS transpose -> full-line
// stores. No k_se kernel, no A/mid HBM traffic.
__global__ void __launch_bounds__(512, 4)
k_fused(const unsigned short* __restrict__ t, const unsigned short* __restrict__ w_t,
        const unsigned short* __restrict__ w1t, const float* __restrict__ se_w2,
        float* __restrict__ out) {
    int blk = swz64(blockIdx.x);
    int b = blk >> 6, tile = blk & 63;
    int ty0 = (tile >> 2) << 3, tx0 = (tile & 3) << 5;
    int tid = threadIdx.x, lane = tid & 63, wave = tid >> 6;
    int wy = wave >> 1, wx = wave & 1;
    int n = lane & 15, q = lane >> 4, qc = q << 3;
    __shared__ __align__(16) char smem[LDSZ];
    float* fb  = (float*)smem;                 // epilogue reuse (36864B < MIDOFF)
    float* mid = (float*)(smem + MIDOFF);      // [340 px][MIDS]
    float* w2l = (float*)(smem + W2OFF);       // [9 tap][16 ch]

    // ---- stage 12x36 pixel tile (row/col clamped into t; clamped data only
    // feeds border-masked mid pixels) ----
    const unsigned short* tbb = t + (size_t)b * TW * TW * C_;
    for (int i = tid; i < STG_H * STG_W * 8; i += 512) {
        int row = i / (STG_W * 8), r = i % (STG_W * 8), px = r >> 3, ch = r & 7;
        int tr = ty0 - 1 + row; tr = tr < 0 ? 0 : (tr > TW - 1 ? TW - 1 : tr);
        int tc = tx0 - 1 + px;  tc = tc < 0 ? 0 : (tc > TW - 1 ? TW - 1 : tc);
        uint4 v = *(const uint4*)(tbb + ((size_t)tr * TW + tc) * C_ + ch * 8);
        *(uint4*)(smem + (row * STG_W + px) * 128 + ((ch ^ (px & 7)) << 4)) = v;
    }
    if (tid < 144) w2l[tid] = se_w2[(tid & 15) * 9 + (tid >> 4)];
    __syncthreads();

    // ---- conv1 -> mid (relu + border mask). 340 mid px (10x34) in 22 groups
    // of 16; wave handles g = wave + 8*gi. ----
    for (int gi = 0; gi < 3; ++gi) {
        int g = wave + (gi << 3);
        if (g < 22) {
            int p = g * 16 + n; if (p > 339) p = 339;
            int mr = p / 34, mc = p - mr * 34;
            f32x4 a1 = {};
            #pragma unroll
            for (int tap = 0; tap < 9; ++tap) {
                int ki = tap / 3, kj = tap % 3;
                int sc = mc + kj;
                int sb = ((mr + ki) * STG_W + sc) * 128;
                uint4 u0 = *(const uint4*)(w1t + (tap * 16 + n) * C_ + qc);
                uint4 u1 = *(const uint4*)(w1t + (tap * 16 + n) * C_ + 32 + qc);
                bf16x8 b0 = *(const bf16x8*)(smem + sb + ((q ^ (sc & 7)) << 4));
                bf16x8 b1 = *(const bf16x8*)(smem + sb + (((4 + q) ^ (sc & 7)) << 4));
                a1 = __builtin_amdgcn_mfma_f32_16x16x32_bf16(
                         __builtin_bit_cast(bf16x8, u0), b0, a1, 0, 0, 0);
                a1 = __builtin_amdgcn_mfma_f32_16x16x32_bf16(
                         __builtin_bit_cast(bf16x8, u1), b1, a1, 0, 0, 0);
            }
            int my = ty0 - 1 + mr, mx = tx0 - 1 + mc;
            bool valid = (my >= 0) && (my < 128) && (mx >= 0) && (mx < 128);
            if (g < 21 || n < 4) {   // skip duplicate lanes of partial group 21
                #pragma unroll
                for (int r = 0; r < 4; ++r)
                    mid[p * MIDS + (q << 2) + r] = valid ? fmaxf(a1[r], 0.f) : 0.f;
            }
        }
    }

    // ---- main conv (stage coords shifted +1 vs pre-fusion layout) ----
    f32x4 acc[4][2] = {};
    const unsigned short* wb = w_t + (size_t)b * 9 * C_ * C_;
    #pragma unroll
    for (int tap = 0; tap < 9; ++tap) {
        int ki = tap / 3, kj = tap % 3;
        int xl = (wx << 4) + n + kj + 1;
        int xk = xl & 7;
        #pragma unroll
        for (int half = 0; half < 2; ++half) {
            bf16x8 af[4];
            #pragma unroll
            for (int mt = 0; mt < 4; ++mt) {
                uint4 au = *(const uint4*)(wb + (((tap * 4 + mt) * 2 + half) << 9) + (lane << 3));
                af[mt] = __builtin_bit_cast(bf16x8, au);
            }
            int slot = (((half << 2) + q) ^ xk) << 4;
            #pragma unroll
            for (int j2 = 0; j2 < 2; ++j2) {
                int yl = (wy << 1) + j2 + ki + 1;
                bf16x8 bf = *(const bf16x8*)(smem + (yl * STG_W + xl) * 128 + slot);
                #pragma unroll
                for (int mt = 0; mt < 4; ++mt)
                    acc[mt][j2] = __builtin_amdgcn_mfma_f32_16x16x32_bf16(af[mt], bf, acc[mt][j2], 0, 0, 0);
            }
        }
    }
    __syncthreads();   // mid writes visible; stage reads complete

    // ---- conv2 + sigmoid -> A in registers. Thread covers its 2 output px;
    // channels split across q (4 each), reduced via shfl_xor over lanes. ----
    float4 wq[9];
    #pragma unroll
    for (int tap = 0; tap < 9; ++tap)
        wq[tap] = *(const float4*)&w2l[tap * 16 + (q << 2)];
    float Av[2];
    #pragma unroll
    for (int j2 = 0; j2 < 2; ++j2) {
        float s = 0.f;
        #pragma unroll
        for (int di = 0; di < 3; ++di) {
            #pragma unroll
            for (int dj = 0; dj < 3; ++dj) {
                int p = ((wy << 1) + j2 + di) * 34 + (wx << 4) + n + dj;
                const float* mp = &mid[p * MIDS + (q << 2)];
                float2 m0 = *(const float2*)mp;
                float2 m1 = *(const float2*)(mp + 2);
                float4 wv = wq[di * 3 + dj];
                s = fmaf(m0.x, wv.x, s);
                s = fmaf(m0.y, wv.y, s);
                s = fmaf(m1.x, wv.z, s);
                s = fmaf(m1.y, wv.w, s);
            }
        }
        s += __shfl_xor(s, 16, 64);
        s += __shfl_xor(s, 32, 64);
        Av[j2] = 1.f / (1.f + expf(-s));
    }

    // ---- epilogue: A-scale -> LDS transpose -> full-line dwordx4 stores ----
    #pragma unroll
    for (int j2 = 0; j2 < 2; ++j2) {
        __syncthreads();
        #pragma unroll
        for (int mt = 0; mt < 4; ++mt) {
            #pragma unroll
            for (int r = 0; r < 4; ++r) {
                int o = (mt << 4) + (q << 2) + r;
                fb[((wy << 6) + o) * FBS + (wx << 4) + n] = acc[mt][j2][r] * Av[j2];
            }
        }
        __syncthreads();
        #pragma unroll
        for (int it = 0; it < 4; ++it) {
            int s = it * 512 + tid;
            int row = s >> 3, xq = s & 7;
            int wy2 = row >> 6, o = row & 63;
            float4 v = *(const float4*)&fb[row * FBS + (xq << 2)];
            *(float4*)(out + (((size_t)(b * C_ + o)) << 14) +
                       ((ty0 + (wy2 << 1) + j2) << 7) + tx0 + (xq << 2)) = v;
        }
    }
}

// ---------------------------------------------------------------------------
extern "C" void kernel_launch(void* const* d_in, const int* in_sizes, int n_in,
                              void* d_out, int out_size, void* d_ws, size_t ws_size,
                              hipStream_t stream) {
    const float* x      = (const float*)d_in[0];
    const float* weight = (const float*)d_in[1];
    const float* se_w1  = (const float*)d_in[2];
    const float* se_w2  = (const float*)d_in[3];
    const float* fc_w1  = (const float*)d_in[4];
    const float* fc_w2  = (const float*)d_in[5];
    float* out = (float*)d_out;

    char* ws = (char*)d_ws;
    float* y0            = (float*)ws;                         ws += 4096;
    unsigned short* t    = (unsigned short*)ws;                ws += (size_t)B_ * TW * TW * C_ * 2 + 4096;
    unsigned short* w_t  = (unsigned short*)ws;                ws += (size_t)B_ * 9 * C_ * C_ * 2;
    unsigned short* w1t  = (unsigned short*)ws;

    k_w1t  <<<36, 256, 0, stream>>>(se_w1, w1t, y0);          // zeroes y0 first
    k_tr   <<<B_ * H_, 256, 0, stream>>>(x, t, y0);           // + fused mean
    k_attwt<<<B_ * 4, 256, 0, stream>>>(y0, fc_w1, fc_w2, weight, w_t);
    k_fused<<<B_ * 64, 512, 0, stream>>>(t, w_t, w1t, se_w2, out);
}

// Round 6
// 215.265 us; speedup vs baseline: 1.1717x; 1.0163x over previous
//
#include <hip/hip_runtime.h>
#include <hip/hip_bf16.h>
#include <math.h>

#define B_  16
#define C_  64
#define H_  128
#define W_  128
#define HW_ (H_ * W_)
#define CR_ 4
#define K9C (9 * C_)   // 576
#define TW  130        // transposed buffer spatial dim (128 + 2 halo)
#define FBS 36         // epilogue fb row stride (floats)
#define STG_W 36       // staged tile: 12 rows x 36 cols of pixels (128B each)
#define STG_H 12
#define MIDOFF (STG_H * STG_W * 128)        // 55296; mid region / w_t dbuf
#define MIDS 18                             // mid pixel stride (floats)
#define W2OFF (MIDOFF + 340 * MIDS * 4)     // 55296 + 24480 = 79776
#define LDSZ  (W2OFF + 144 * 4)             // 80352 (<= 81920: 2 blocks/CU)

typedef float f32x4 __attribute__((ext_vector_type(4)));
typedef __bf16 bf16x8 __attribute__((ext_vector_type(8)));

static __device__ __forceinline__ unsigned short f2us(float f) {
    __bf16 h = (__bf16)f;
    return __builtin_bit_cast(unsigned short, h);
}

// XCD-aware bijective swizzle: grid 1024 = 16 batches x 64 tiles; each XCD
// walks whole batches (per-XCD L2 working set = one batch's t = 2.16 MB).
static __device__ __forceinline__ int swz64(int blk) {
    int xcd = blk & 7, i = blk >> 3;
    return ((i >> 6) << 9) + (xcd << 6) + (i & 63);
}

// ---------------------------------------------------------------------------
// K2: x (NCHW fp32) -> t (b, y', x', c) bf16 with zeroed 1-px halo border.
// Also accumulates per-(b,c) sums into y0 (atomic), fused mean.
__global__ void k_tr(const float* __restrict__ x, unsigned short* __restrict__ t,
                     float* __restrict__ y0) {
    int blk = blockIdx.x;
    int b = blk >> 7, y = blk & 127;
    __shared__ unsigned short lds[C_ * TW];
    int tid = threadIdx.x;
    for (int i = tid; i < C_ * 32; i += 256) {
        int c = i >> 5, xq = i & 31;
        float4 v = *(const float4*)(x + (((size_t)(b * C_ + c)) << 14) + (y << 7) + (xq << 2));
        unsigned int p0 = f2us(v.x) | ((unsigned int)f2us(v.y) << 16);
        unsigned int p1 = f2us(v.z) | ((unsigned int)f2us(v.w) << 16);
        *(unsigned int*)&lds[c * TW + (xq << 2)]     = p0;
        *(unsigned int*)&lds[c * TW + (xq << 2) + 2] = p1;
        float s4 = v.x + v.y + v.z + v.w;
        s4 += __shfl_down(s4, 16, 32);
        s4 += __shfl_down(s4, 8, 32);
        s4 += __shfl_down(s4, 4, 32);
        s4 += __shfl_down(s4, 2, 32);
        s4 += __shfl_down(s4, 1, 32);
        if ((tid & 31) == 0) atomicAdd(&y0[b * C_ + c], s4);
    }
    __syncthreads();
    size_t rowbase = ((size_t)(b * TW + y + 1)) * TW * C_;
    for (int j = tid; j < 128 * 16; j += 256) {
        int px = j >> 4, g = j & 15;
        unsigned short a0 = lds[(4 * g + 0) * TW + px];
        unsigned short a1 = lds[(4 * g + 1) * TW + px];
        unsigned short a2 = lds[(4 * g + 2) * TW + px];
        unsigned short a3 = lds[(4 * g + 3) * TW + px];
        uint2 wv;
        wv.x = a0 | ((unsigned int)a1 << 16);
        wv.y = a2 | ((unsigned int)a3 << 16);
        *(uint2*)(t + rowbase + (size_t)(px + 1) * C_ + (g << 2)) = wv;
    }
    if (tid < 16) {
        int px = (tid < 8) ? 0 : (TW - 1);
        int ch = tid & 7;
        uint4 z = {0, 0, 0, 0};
        *(uint4*)(t + rowbase + (size_t)px * C_ + ch * 8) = z;
    }
    if (y == 0) {
        size_t base = (size_t)b * TW * TW * C_;
        uint4 z = {0, 0, 0, 0};
        for (int i = tid; i < TW * C_ / 8; i += 256)
            *(uint4*)(t + base + (size_t)i * 8) = z;
    }
    if (y == 127) {
        size_t base = ((size_t)(b * TW + TW - 1)) * TW * C_;
        uint4 z = {0, 0, 0, 0};
        for (int i = tid; i < TW * C_ / 8; i += 256)
            *(uint4*)(t + base + (size_t)i * 8) = z;
    }
}

// ---------------------------------------------------------------------------
// K3: transpose se_w1 [16][64][9] -> w1t [tap][o][c] bf16. Also zeroes y0.
__global__ void k_w1t(const float* __restrict__ se_w1, unsigned short* __restrict__ w1t,
                      float* __restrict__ y0) {
    if (blockIdx.x < 4) y0[(blockIdx.x << 8) | threadIdx.x] = 0.f;
    int idx = blockIdx.x * 256 + threadIdx.x;
    int tap = idx >> 10, o = (idx >> 6) & 15, c = idx & 63;
    w1t[idx] = f2us(se_w1[(o * C_ + c) * 9 + tap]);
}

// ---------------------------------------------------------------------------
// K4: fused channel attention + w_t build (MFMA-fragment-ordered). grid = B*4.
__global__ void k_attwt(const float* __restrict__ y0,
                        const float* __restrict__ fc_w1,
                        const float* __restrict__ fc_w2,
                        const float* __restrict__ weight,
                        unsigned short* __restrict__ w_t) {
    int blk = blockIdx.x;
    int b = blk >> 2, mt = blk & 3;
    __shared__ float sy0[C_];
    __shared__ float sh[CR_];
    __shared__ float ssy[K9C];
    __shared__ float sw[16 * 576];
    int tid = threadIdx.x;
    if (tid < C_) sy0[tid] = y0[b * C_ + tid] * (1.0f / (float)HW_);
    const float* wsrc = weight + (size_t)(mt * 16) * 576;
    for (int i = tid; i < 16 * 576; i += 256) sw[i] = wsrc[i];
    __syncthreads();
    if (tid < CR_) {
        float s = 0.f;
        for (int c = 0; c < C_; ++c) s = fmaf(fc_w1[tid * C_ + c], sy0[c], s);
        sh[tid] = fmaxf(s, 0.f);
    }
    __syncthreads();
    for (int i = tid; i < K9C; i += 256) {
        float s = 0.f;
        #pragma unroll
        for (int j = 0; j < CR_; ++j) s = fmaf(fc_w2[i * CR_ + j], sh[j], s);
        ssy[i] = 1.f / (1.f + expf(-s));
    }
    __syncthreads();
    unsigned short* wb = w_t + (size_t)b * 9 * C_ * C_;
    for (int ii = tid; ii < 4608; ii += 256) {
        int i = ii << 1;
        int tap = i >> 10, r = i & 1023;
        int half = r >> 9, lane = (r >> 3) & 63, e = r & 7;
        int o = lane & 15;
        int c = half * 32 + ((lane >> 4) << 3) + e;
        float v0 = sw[o * 576 + c * 9 + tap] * ssy[c * 9 + tap];
        float v1 = sw[o * 576 + (c + 1) * 9 + tap] * ssy[(c + 1) * 9 + tap];
        unsigned int pk = f2us(v0) | ((unsigned int)f2us(v1) << 16);
        *(unsigned int*)(wb + ((tap * 4 + mt) * 2 + half) * 512 + lane * 8 + e) = pk;
    }
}

// ---------------------------------------------------------------------------
// K5: FULLY FUSED main+SE, with w_t LDS-staged per tap.
// Order: stage x-tile -> MAIN conv (w_t double-buffered via global_load_lds
// into the future mid region; af = conflict-free linear ds_read_b128) ->
// conv1 -> mid (overwrites dbuf) -> conv2+sigmoid in regs -> epilogue.
// Cuts af L2 traffic 8x (1.15 MB -> 144 KB per block): was ~34 us of per-XCD
// L2 bandwidth.
__global__ void __launch_bounds__(512, 4)
k_fused(const unsigned short* __restrict__ t, const unsigned short* __restrict__ w_t,
        const unsigned short* __restrict__ w1t, const float* __restrict__ se_w2,
        float* __restrict__ out) {
    int blk = swz64(blockIdx.x);
    int b = blk >> 6, tile = blk & 63;
    int ty0 = (tile >> 2) << 3, tx0 = (tile & 3) << 5;
    int tid = threadIdx.x, lane = tid & 63, wave = tid >> 6;
    int wy = wave >> 1, wx = wave & 1;
    int n = lane & 15, q = lane >> 4, qc = q << 3;
    __shared__ __align__(16) char smem[LDSZ];
    float* fb  = (float*)smem;                 // epilogue reuse (36864B < MIDOFF)
    float* mid = (float*)(smem + MIDOFF);      // [340 px][MIDS] (after main conv)
    float* w2l = (float*)(smem + W2OFF);       // [9 tap][16 ch]

    // ---- stage 12x36 pixel tile (row/col clamped into t; clamped data only
    // feeds border-masked mid pixels) ----
    const unsigned short* tbb = t + (size_t)b * TW * TW * C_;
    for (int i = tid; i < STG_H * STG_W * 8; i += 512) {
        int row = i / (STG_W * 8), r = i % (STG_W * 8), px = r >> 3, ch = r & 7;
        int tr = ty0 - 1 + row; tr = tr < 0 ? 0 : (tr > TW - 1 ? TW - 1 : tr);
        int tc = tx0 - 1 + px;  tc = tc < 0 ? 0 : (tc > TW - 1 ? TW - 1 : tc);
        uint4 v = *(const uint4*)(tbb + ((size_t)tr * TW + tc) * C_ + ch * 8);
        *(uint4*)(smem + (row * STG_W + px) * 128 + ((ch ^ (px & 7)) << 4)) = v;
    }
    if (tid < 144) w2l[tid] = se_w2[(tid & 15) * 9 + (tid >> 4)];

    // ---- main conv with w_t double-buffered through LDS ----
    // Per tap: 8192 B in fragment order; wave w stages slice w (64 lanes x 16B,
    // linear dest per global_load_lds semantics). Reads are lane*16 linear ->
    // conflict-free ds_read_b128.
    const unsigned short* wb = w_t + (size_t)b * 9 * C_ * C_;
    #define STAGE_WT(tp) \
        __builtin_amdgcn_global_load_lds( \
            (const __attribute__((address_space(1))) void*)(wb + (tp) * 4096 + (wave << 9) + (lane << 3)), \
            (__attribute__((address_space(3))) void*)(smem + MIDOFF + ((tp) & 1) * 8192 + (wave << 10)), \
            16, 0, 0)
    STAGE_WT(0);
    __syncthreads();   // x-stage visible + tap0 staged (auto vmcnt/lgkm drain)

    f32x4 acc[4][2] = {};
    #pragma unroll
    for (int tap = 0; tap < 9; ++tap) {
        if (tap < 8) STAGE_WT(tap + 1);   // prefetch into other buf
        int ki = tap / 3, kj = tap % 3;
        int xl = (wx << 4) + n + kj + 1;
        int xk = xl & 7;
        const char* tapbuf = smem + MIDOFF + (tap & 1) * 8192;
        #pragma unroll
        for (int half = 0; half < 2; ++half) {
            bf16x8 af[4];
            #pragma unroll
            for (int mt = 0; mt < 4; ++mt) {
                uint4 au = *(const uint4*)(tapbuf + (((mt << 1) + half) << 10) + (lane << 4));
                af[mt] = __builtin_bit_cast(bf16x8, au);
            }
            int slot = (((half << 2) + q) ^ xk) << 4;
            #pragma unroll
            for (int j2 = 0; j2 < 2; ++j2) {
                int yl = (wy << 1) + j2 + ki + 1;
                bf16x8 bf = *(const bf16x8*)(smem + (yl * STG_W + xl) * 128 + slot);
                #pragma unroll
                for (int mt = 0; mt < 4; ++mt)
                    acc[mt][j2] = __builtin_amdgcn_mfma_f32_16x16x32_bf16(af[mt], bf, acc[mt][j2], 0, 0, 0);
            }
        }
        __syncthreads();   // drains stage(tap+1); all waves done with buf[tap&1]
    }
    #undef STAGE_WT

    // ---- conv1 -> mid (relu + border mask), overwrites the w_t dbuf region.
    // 340 mid px (10x34) in 22 groups of 16; wave handles g = wave + 8*gi. ----
    for (int gi = 0; gi < 3; ++gi) {
        int g = wave + (gi << 3);
        if (g < 22) {
            int p = g * 16 + n; if (p > 339) p = 339;
            int mr = p / 34, mc = p - mr * 34;
            f32x4 a1 = {};
            #pragma unroll
            for (int tap = 0; tap < 9; ++tap) {
                int ki = tap / 3, kj = tap % 3;
                int sc = mc + kj;
                int sb = ((mr + ki) * STG_W + sc) * 128;
                uint4 u0 = *(const uint4*)(w1t + (tap * 16 + n) * C_ + qc);
                uint4 u1 = *(const uint4*)(w1t + (tap * 16 + n) * C_ + 32 + qc);
                bf16x8 b0 = *(const bf16x8*)(smem + sb + ((q ^ (sc & 7)) << 4));
                bf16x8 b1 = *(const bf16x8*)(smem + sb + (((4 + q) ^ (sc & 7)) << 4));
                a1 = __builtin_amdgcn_mfma_f32_16x16x32_bf16(
                         __builtin_bit_cast(bf16x8, u0), b0, a1, 0, 0, 0);
                a1 = __builtin_amdgcn_mfma_f32_16x16x32_bf16(
                         __builtin_bit_cast(bf16x8, u1), b1, a1, 0, 0, 0);
            }
            int my = ty0 - 1 + mr, mx = tx0 - 1 + mc;
            bool valid = (my >= 0) && (my < 128) && (mx >= 0) && (mx < 128);
            if (g < 21 || n < 4) {   // skip duplicate lanes of partial group 21
                #pragma unroll
                for (int r = 0; r < 4; ++r)
                    mid[p * MIDS + (q << 2) + r] = valid ? fmaxf(a1[r], 0.f) : 0.f;
            }
        }
    }
    __syncthreads();   // mid visible

    // ---- conv2 + sigmoid -> A in registers (q-split channels + shfl reduce) ----
    float4 wq[9];
    #pragma unroll
    for (int tap = 0; tap < 9; ++tap)
        wq[tap] = *(const float4*)&w2l[tap * 16 + (q << 2)];
    float Av[2];
    #pragma unroll
    for (int j2 = 0; j2 < 2; ++j2) {
        float s = 0.f;
        #pragma unroll
        for (int di = 0; di < 3; ++di) {
            #pragma unroll
            for (int dj = 0; dj < 3; ++dj) {
                int p = ((wy << 1) + j2 + di) * 34 + (wx << 4) + n + dj;
                const float* mp = &mid[p * MIDS + (q << 2)];
                float2 m0 = *(const float2*)mp;
                float2 m1 = *(const float2*)(mp + 2);
                float4 wv = wq[di * 3 + dj];
                s = fmaf(m0.x, wv.x, s);
                s = fmaf(m0.y, wv.y, s);
                s = fmaf(m1.x, wv.z, s);
                s = fmaf(m1.y, wv.w, s);
            }
        }
        s += __shfl_xor(s, 16, 64);
        s += __shfl_xor(s, 32, 64);
        Av[j2] = 1.f / (1.f + expf(-s));
    }

    // ---- epilogue: A-scale -> LDS transpose -> full-line dwordx4 stores ----
    #pragma unroll
    for (int j2 = 0; j2 < 2; ++j2) {
        __syncthreads();
        #pragma unroll
        for (int mt = 0; mt < 4; ++mt) {
            #pragma unroll
            for (int r = 0; r < 4; ++r) {
                int o = (mt << 4) + (q << 2) + r;
                fb[((wy << 6) + o) * FBS + (wx << 4) + n] = acc[mt][j2][r] * Av[j2];
            }
        }
        __syncthreads();
        #pragma unroll
        for (int it = 0; it < 4; ++it) {
            int s = it * 512 + tid;
            int row = s >> 3, xq = s & 7;
            int wy2 = row >> 6, o = row & 63;
            float4 v = *(const float4*)&fb[row * FBS + (xq << 2)];
            *(float4*)(out + (((size_t)(b * C_ + o)) << 14) +
                       ((ty0 + (wy2 << 1) + j2) << 7) + tx0 + (xq << 2)) = v;
        }
    }
}

// ---------------------------------------------------------------------------
extern "C" void kernel_launch(void* const* d_in, const int* in_sizes, int n_in,
                              void* d_out, int out_size, void* d_ws, size_t ws_size,
                              hipStream_t stream) {
    const float* x      = (const float*)d_in[0];
    const float* weight = (const float*)d_in[1];
    const float* se_w1  = (const float*)d_in[2];
    const float* se_w2  = (const float*)d_in[3];
    const float* fc_w1  = (const float*)d_in[4];
    const float* fc_w2  = (const float*)d_in[5];
    float* out = (float*)d_out;

    char* ws = (char*)d_ws;
    float* y0            = (float*)ws;                         ws += 4096;
    unsigned short* t    = (unsigned short*)ws;                ws += (size_t)B_ * TW * TW * C_ * 2 + 4096;
    unsigned short* w_t  = (unsigned short*)ws;                ws += (size_t)B_ * 9 * C_ * C_ * 2;
    unsigned short* w1t  = (unsigned short*)ws;

    k_w1t  <<<36, 256, 0, stream>>>(se_w1, w1t, y0);          // zeroes y0 first
    k_tr   <<<B_ * H_, 256, 0, stream>>>(x, t, y0);           // + fused mean
    k_attwt<<<B_ * 4, 256, 0, stream>>>(y0, fc_w1, fc_w2, weight, w_t);
    k_fused<<<B_ * 64, 512, 0, stream>>>(t, w_t, w1t, se_w2, out);
}

// Round 7
// 193.437 us; speedup vs baseline: 1.3039x; 1.1128x over previous
//
#include <hip/hip_runtime.h>
#include <hip/hip_bf16.h>
#include <math.h>

#define B_  16
#define C_  64
#define H_  128
#define W_  128
#define HW_ (H_ * W_)
#define CR_ 4
#define K9C (9 * C_)   // 576
#define TW  130        // transposed buffer spatial dim (128 + 2 halo)
#define FBS 36         // epilogue fb row stride (floats)
#define STG_W 36       // staged tile: 12 rows x 36 cols of pixels (128B each)
#define STG_H 12
#define MIDOFF (STG_H * STG_W * 128)        // 55296; w_t triple-buf, later mid
#define MIDS 18                             // mid pixel stride (floats)
#define WTB 8192                            // one tap of w_t in LDS
#define W2OFF (MIDOFF + 3 * WTB)            // 79872
#define LDSZ  (W2OFF + 144 * 4)             // 80448 (<= 81920: 2 blocks/CU)

typedef float f32x4 __attribute__((ext_vector_type(4)));
typedef __bf16 bf16x8 __attribute__((ext_vector_type(8)));

static __device__ __forceinline__ unsigned short f2us(float f) {
    __bf16 h = (__bf16)f;
    return __builtin_bit_cast(unsigned short, h);
}

// XCD-aware bijective swizzle: grid 1024 = 16 batches x 64 tiles; each XCD
// walks whole batches (per-XCD L2 working set = one batch's t = 2.16 MB).
static __device__ __forceinline__ int swz64(int blk) {
    int xcd = blk & 7, i = blk >> 3;
    return ((i >> 6) << 9) + (xcd << 6) + (i & 63);
}

// ---------------------------------------------------------------------------
// K2: x (NCHW fp32) -> t (b, y', x', c) bf16 with zeroed 1-px halo border.
// Also accumulates per-(b,c) sums into y0 (atomic), fused mean.
__global__ void k_tr(const float* __restrict__ x, unsigned short* __restrict__ t,
                     float* __restrict__ y0) {
    int blk = blockIdx.x;
    int b = blk >> 7, y = blk & 127;
    __shared__ unsigned short lds[C_ * TW];
    int tid = threadIdx.x;
    for (int i = tid; i < C_ * 32; i += 256) {
        int c = i >> 5, xq = i & 31;
        float4 v = *(const float4*)(x + (((size_t)(b * C_ + c)) << 14) + (y << 7) + (xq << 2));
        unsigned int p0 = f2us(v.x) | ((unsigned int)f2us(v.y) << 16);
        unsigned int p1 = f2us(v.z) | ((unsigned int)f2us(v.w) << 16);
        *(unsigned int*)&lds[c * TW + (xq << 2)]     = p0;
        *(unsigned int*)&lds[c * TW + (xq << 2) + 2] = p1;
        float s4 = v.x + v.y + v.z + v.w;
        s4 += __shfl_down(s4, 16, 32);
        s4 += __shfl_down(s4, 8, 32);
        s4 += __shfl_down(s4, 4, 32);
        s4 += __shfl_down(s4, 2, 32);
        s4 += __shfl_down(s4, 1, 32);
        if ((tid & 31) == 0) atomicAdd(&y0[b * C_ + c], s4);
    }
    __syncthreads();
    size_t rowbase = ((size_t)(b * TW + y + 1)) * TW * C_;
    for (int j = tid; j < 128 * 16; j += 256) {
        int px = j >> 4, g = j & 15;
        unsigned short a0 = lds[(4 * g + 0) * TW + px];
        unsigned short a1 = lds[(4 * g + 1) * TW + px];
        unsigned short a2 = lds[(4 * g + 2) * TW + px];
        unsigned short a3 = lds[(4 * g + 3) * TW + px];
        uint2 wv;
        wv.x = a0 | ((unsigned int)a1 << 16);
        wv.y = a2 | ((unsigned int)a3 << 16);
        *(uint2*)(t + rowbase + (size_t)(px + 1) * C_ + (g << 2)) = wv;
    }
    if (tid < 16) {
        int px = (tid < 8) ? 0 : (TW - 1);
        int ch = tid & 7;
        uint4 z = {0, 0, 0, 0};
        *(uint4*)(t + rowbase + (size_t)px * C_ + ch * 8) = z;
    }
    if (y == 0) {
        size_t base = (size_t)b * TW * TW * C_;
        uint4 z = {0, 0, 0, 0};
        for (int i = tid; i < TW * C_ / 8; i += 256)
            *(uint4*)(t + base + (size_t)i * 8) = z;
    }
    if (y == 127) {
        size_t base = ((size_t)(b * TW + TW - 1)) * TW * C_;
        uint4 z = {0, 0, 0, 0};
        for (int i = tid; i < TW * C_ / 8; i += 256)
            *(uint4*)(t + base + (size_t)i * 8) = z;
    }
}

// ---------------------------------------------------------------------------
// K4: fused channel attention + w_t build (MFMA-fragment-ordered) + w1t
// transpose (folded from the old k_w1t; block 0 does it). grid = B*4.
__global__ void k_attwt(const float* __restrict__ y0,
                        const float* __restrict__ fc_w1,
                        const float* __restrict__ fc_w2,
                        const float* __restrict__ weight,
                        const float* __restrict__ se_w1,
                        unsigned short* __restrict__ w_t,
                        unsigned short* __restrict__ w1t) {
    int blk = blockIdx.x;
    int b = blk >> 2, mt = blk & 3;
    __shared__ float sy0[C_];
    __shared__ float sh[CR_];
    __shared__ float ssy[K9C];
    __shared__ float sw[16 * 576];
    int tid = threadIdx.x;
    if (blk == 0) {
        for (int i = tid; i < 9 * 16 * C_; i += 256) {
            int tap = i >> 10, o = (i >> 6) & 15, c = i & 63;
            w1t[i] = f2us(se_w1[(o * C_ + c) * 9 + tap]);
        }
    }
    if (tid < C_) sy0[tid] = y0[b * C_ + tid] * (1.0f / (float)HW_);
    const float* wsrc = weight + (size_t)(mt * 16) * 576;
    for (int i = tid; i < 16 * 576; i += 256) sw[i] = wsrc[i];
    __syncthreads();
    if (tid < CR_) {
        float s = 0.f;
        for (int c = 0; c < C_; ++c) s = fmaf(fc_w1[tid * C_ + c], sy0[c], s);
        sh[tid] = fmaxf(s, 0.f);
    }
    __syncthreads();
    for (int i = tid; i < K9C; i += 256) {
        float s = 0.f;
        #pragma unroll
        for (int j = 0; j < CR_; ++j) s = fmaf(fc_w2[i * CR_ + j], sh[j], s);
        ssy[i] = 1.f / (1.f + expf(-s));
    }
    __syncthreads();
    unsigned short* wb = w_t + (size_t)b * 9 * C_ * C_;
    for (int ii = tid; ii < 4608; ii += 256) {
        int i = ii << 1;
        int tap = i >> 10, r = i & 1023;
        int half = r >> 9, lane = (r >> 3) & 63, e = r & 7;
        int o = lane & 15;
        int c = half * 32 + ((lane >> 4) << 3) + e;
        float v0 = sw[o * 576 + c * 9 + tap] * ssy[c * 9 + tap];
        float v1 = sw[o * 576 + (c + 1) * 9 + tap] * ssy[(c + 1) * 9 + tap];
        unsigned int pk = f2us(v0) | ((unsigned int)f2us(v1) << 16);
        *(unsigned int*)(wb + ((tap * 4 + mt) * 2 + half) * 512 + lane * 8 + e) = pk;
    }
}

// ---------------------------------------------------------------------------
// K5: FULLY FUSED main+SE.
// Changes this round:
//  - w_t pipeline 3-deep with counted s_waitcnt vmcnt(1) + raw s_barrier
//    (never vmcnt(0) in the main loop; the old per-tap __syncthreads drained
//    the just-issued prefetch with only ~80cyc of cover vs ~250cyc L2).
//  - conv1 loop reordered tap-outer: w1t fragment loaded ONCE per tap
//    (18 global loads/thread vs 54, each covered by 6 MFMAs).
//  - setprio(1) around the main-conv MFMA cluster (T5).
__global__ void __launch_bounds__(512, 4)
k_fused(const unsigned short* __restrict__ t, const unsigned short* __restrict__ w_t,
        const unsigned short* __restrict__ w1t, const float* __restrict__ se_w2,
        float* __restrict__ out) {
    int blk = swz64(blockIdx.x);
    int b = blk >> 6, tile = blk & 63;
    int ty0 = (tile >> 2) << 3, tx0 = (tile & 3) << 5;
    int tid = threadIdx.x, lane = tid & 63, wave = tid >> 6;
    int wy = wave >> 1, wx = wave & 1;
    int n = lane & 15, q = lane >> 4, qc = q << 3;
    __shared__ __align__(16) char smem[LDSZ];
    float* fb  = (float*)smem;                 // epilogue reuse (36864B < MIDOFF)
    float* mid = (float*)(smem + MIDOFF);      // [340 px][MIDS] (after main conv)
    float* w2l = (float*)(smem + W2OFF);       // [9 tap][16 ch]

    // ---- stage 12x36 pixel tile (row/col clamped into t; clamped data only
    // feeds border-masked mid pixels) ----
    const unsigned short* tbb = t + (size_t)b * TW * TW * C_;
    for (int i = tid; i < STG_H * STG_W * 8; i += 512) {
        int row = i / (STG_W * 8), r = i % (STG_W * 8), px = r >> 3, ch = r & 7;
        int tr = ty0 - 1 + row; tr = tr < 0 ? 0 : (tr > TW - 1 ? TW - 1 : tr);
        int tc = tx0 - 1 + px;  tc = tc < 0 ? 0 : (tc > TW - 1 ? TW - 1 : tc);
        uint4 v = *(const uint4*)(tbb + ((size_t)tr * TW + tc) * C_ + ch * 8);
        *(uint4*)(smem + (row * STG_W + px) * 128 + ((ch ^ (px & 7)) << 4)) = v;
    }
    if (tid < 144) w2l[tid] = se_w2[(tid & 15) * 9 + (tid >> 4)];

    // ---- main conv; w_t triple-buffered through LDS, counted-vmcnt drain ----
    const unsigned short* wb = w_t + (size_t)b * 9 * C_ * C_;
    #define STAGE_WT(tp) \
        __builtin_amdgcn_global_load_lds( \
            (const __attribute__((address_space(1))) void*)(wb + (tp) * 4096 + (wave << 9) + (lane << 3)), \
            (__attribute__((address_space(3))) void*)(smem + MIDOFF + ((tp) % 3) * WTB + (wave << 10)), \
            16, 0, 0)
    STAGE_WT(0);
    STAGE_WT(1);
    __syncthreads();   // x-stage + w2l visible; stages 0,1 fully drained

    f32x4 acc[4][2] = {};
    #pragma unroll
    for (int tap = 0; tap < 9; ++tap) {
        if (tap) {
            // own slice of stage(tap) landed: keep at most 1 newer in flight
            if (tap < 8) asm volatile("s_waitcnt vmcnt(1)" ::: "memory");
            else         asm volatile("s_waitcnt vmcnt(0)" ::: "memory");
            __builtin_amdgcn_s_barrier();              // all waves' slices landed
            __builtin_amdgcn_sched_barrier(0);         // no hoisting past barrier
        }
        if (tap < 7) STAGE_WT(tap + 2);   // overwrites buf read at tap-1 (safe)
        int ki = tap / 3, kj = tap % 3;
        int xl = (wx << 4) + n + kj + 1;
        int xk = xl & 7;
        const char* tapbuf = smem + MIDOFF + (tap % 3) * WTB;
        __builtin_amdgcn_s_setprio(1);
        #pragma unroll
        for (int half = 0; half < 2; ++half) {
            bf16x8 af[4];
            #pragma unroll
            for (int mt = 0; mt < 4; ++mt) {
                uint4 au = *(const uint4*)(tapbuf + (((mt << 1) + half) << 10) + (lane << 4));
                af[mt] = __builtin_bit_cast(bf16x8, au);
            }
            int slot = (((half << 2) + q) ^ xk) << 4;
            #pragma unroll
            for (int j2 = 0; j2 < 2; ++j2) {
                int yl = (wy << 1) + j2 + ki + 1;
                bf16x8 bf = *(const bf16x8*)(smem + (yl * STG_W + xl) * 128 + slot);
                #pragma unroll
                for (int mt = 0; mt < 4; ++mt)
                    acc[mt][j2] = __builtin_amdgcn_mfma_f32_16x16x32_bf16(af[mt], bf, acc[mt][j2], 0, 0, 0);
            }
        }
        __builtin_amdgcn_s_setprio(0);
    }
    #undef STAGE_WT
    __syncthreads();   // all buf reads done; region becomes mid

    // ---- conv1 -> mid (relu + border mask), tap-outer (w1t loaded 18x not 54x)
    int mr[3], mc[3], pp[3];
    bool on[3];
    #pragma unroll
    for (int i = 0; i < 3; ++i) {
        int g = wave + (i << 3);
        on[i] = (g < 22);
        int p = g * 16 + n; if (p > 339) p = 339;
        pp[i] = p; mr[i] = p / 34; mc[i] = p - mr[i] * 34;
    }
    f32x4 a1_0 = {}, a1_1 = {}, a1_2 = {};
    #pragma unroll
    for (int tap = 0; tap < 9; ++tap) {
        int ki = tap / 3, kj = tap % 3;
        uint4 u0 = *(const uint4*)(w1t + (tap * 16 + n) * C_ + qc);
        uint4 u1 = *(const uint4*)(w1t + (tap * 16 + n) * C_ + 32 + qc);
        bf16x8 af0 = __builtin_bit_cast(bf16x8, u0);
        bf16x8 af1 = __builtin_bit_cast(bf16x8, u1);
        #pragma unroll
        for (int i = 0; i < 3; ++i) {
            if (on[i]) {
                int sc = mc[i] + kj;
                int sb = ((mr[i] + ki) * STG_W + sc) * 128;
                bf16x8 b0 = *(const bf16x8*)(smem + sb + ((q ^ (sc & 7)) << 4));
                bf16x8 b1 = *(const bf16x8*)(smem + sb + (((4 + q) ^ (sc & 7)) << 4));
                f32x4 t0 = (i == 0) ? a1_0 : (i == 1) ? a1_1 : a1_2;
                t0 = __builtin_amdgcn_mfma_f32_16x16x32_bf16(af0, b0, t0, 0, 0, 0);
                t0 = __builtin_amdgcn_mfma_f32_16x16x32_bf16(af1, b1, t0, 0, 0, 0);
                if (i == 0) a1_0 = t0; else if (i == 1) a1_1 = t0; else a1_2 = t0;
            }
        }
    }
    #pragma unroll
    for (int i = 0; i < 3; ++i) {
        int g = wave + (i << 3);
        if (on[i] && (g < 21 || n < 4)) {   // skip duplicate lanes of group 21
            int my = ty0 - 1 + mr[i], mx = tx0 - 1 + mc[i];
            bool valid = (my >= 0) && (my < 128) && (mx >= 0) && (mx < 128);
            f32x4 av = (i == 0) ? a1_0 : (i == 1) ? a1_1 : a1_2;
            #pragma unroll
            for (int r = 0; r < 4; ++r)
                mid[pp[i] * MIDS + (q << 2) + r] = valid ? fmaxf(av[r], 0.f) : 0.f;
        }
    }
    __syncthreads();   // mid visible

    // ---- conv2 + sigmoid -> A in registers (q-split channels + shfl reduce) ----
    float4 wq[9];
    #pragma unroll
    for (int tap = 0; tap < 9; ++tap)
        wq[tap] = *(const float4*)&w2l[tap * 16 + (q << 2)];
    float Av[2];
    #pragma unroll
    for (int j2 = 0; j2 < 2; ++j2) {
        float s = 0.f;
        #pragma unroll
        for (int di = 0; di < 3; ++di) {
            #pragma unroll
            for (int dj = 0; dj < 3; ++dj) {
                int p = ((wy << 1) + j2 + di) * 34 + (wx << 4) + n + dj;
                const float* mp = &mid[p * MIDS + (q << 2)];
                float2 m0 = *(const float2*)mp;
                float2 m1 = *(const float2*)(mp + 2);
                float4 wv = wq[di * 3 + dj];
                s = fmaf(m0.x, wv.x, s);
                s = fmaf(m0.y, wv.y, s);
                s = fmaf(m1.x, wv.z, s);
                s = fmaf(m1.y, wv.w, s);
            }
        }
        s += __shfl_xor(s, 16, 64);
        s += __shfl_xor(s, 32, 64);
        Av[j2] = 1.f / (1.f + expf(-s));
    }

    // ---- epilogue: A-scale -> LDS transpose -> full-line dwordx4 stores ----
    #pragma unroll
    for (int j2 = 0; j2 < 2; ++j2) {
        __syncthreads();
        #pragma unroll
        for (int mt = 0; mt < 4; ++mt) {
            #pragma unroll
            for (int r = 0; r < 4; ++r) {
                int o = (mt << 4) + (q << 2) + r;
                fb[((wy << 6) + o) * FBS + (wx << 4) + n] = acc[mt][j2][r] * Av[j2];
            }
        }
        __syncthreads();
        #pragma unroll
        for (int it = 0; it < 4; ++it) {
            int s = it * 512 + tid;
            int row = s >> 3, xq = s & 7;
            int wy2 = row >> 6, o = row & 63;
            float4 v = *(const float4*)&fb[row * FBS + (xq << 2)];
            *(float4*)(out + (((size_t)(b * C_ + o)) << 14) +
                       ((ty0 + (wy2 << 1) + j2) << 7) + tx0 + (xq << 2)) = v;
        }
    }
}

// ---------------------------------------------------------------------------
extern "C" void kernel_launch(void* const* d_in, const int* in_sizes, int n_in,
                              void* d_out, int out_size, void* d_ws, size_t ws_size,
                              hipStream_t stream) {
    const float* x      = (const float*)d_in[0];
    const float* weight = (const float*)d_in[1];
    const float* se_w1  = (const float*)d_in[2];
    const float* se_w2  = (const float*)d_in[3];
    const float* fc_w1  = (const float*)d_in[4];
    const float* fc_w2  = (const float*)d_in[5];
    float* out = (float*)d_out;

    char* ws = (char*)d_ws;
    float* y0            = (float*)ws;                         ws += 4096;
    unsigned short* t    = (unsigned short*)ws;                ws += (size_t)B_ * TW * TW * C_ * 2 + 4096;
    unsigned short* w_t  = (unsigned short*)ws;                ws += (size_t)B_ * 9 * C_ * C_ * 2;
    unsigned short* w1t  = (unsigned short*)ws;

    hipMemsetAsync(y0, 0, 4096, stream);                      // zero mean accum
    k_tr   <<<B_ * H_, 256, 0, stream>>>(x, t, y0);           // + fused mean
    k_attwt<<<B_ * 4, 256, 0, stream>>>(y0, fc_w1, fc_w2, weight, se_w1, w_t, w1t);
    k_fused<<<B_ * 64, 512, 0, stream>>>(t, w_t, w1t, se_w2, out);
}

// Round 8
// 175.312 us; speedup vs baseline: 1.4387x; 1.1034x over previous
//
#include <hip/hip_runtime.h>
#include <hip/hip_bf16.h>
#include <math.h>

#define B_  16
#define C_  64
#define H_  128
#define W_  128
#define HW_ (H_ * W_)
#define CR_ 4
#define K9C (9 * C_)   // 576
#define TW  130        // transposed buffer spatial dim (128 + 2 halo)
#define FBS 36         // epilogue fb row stride (floats)
#define STG_W 36       // staged tile: 12 rows x 36 cols of pixels (128B each)
#define STG_H 12
#define MIDOFF (STG_H * STG_W * 128)        // 55296; w_t triple-buf, later mid
#define MIDS 18                             // mid pixel stride (floats)
#define WTB 8192                            // one tap of w_t in LDS
#define W2OFF (MIDOFF + 3 * WTB)            // 79872
#define LDSZ  (W2OFF + 144 * 4)             // 80448 (<= 81920: 2 blocks/CU)

typedef float f32x4 __attribute__((ext_vector_type(4)));
typedef __bf16 bf16x8 __attribute__((ext_vector_type(8)));

static __device__ __forceinline__ unsigned short f2us(float f) {
    __bf16 h = (__bf16)f;
    return __builtin_bit_cast(unsigned short, h);
}

// XCD-aware bijective swizzle: grid 1024 = 16 batches x 64 tiles; each XCD
// walks whole batches (per-XCD L2 working set = one batch's t = 2.16 MB).
static __device__ __forceinline__ int swz64(int blk) {
    int xcd = blk & 7, i = blk >> 3;
    return ((i >> 6) << 9) + (xcd << 6) + (i & 63);
}

// ---------------------------------------------------------------------------
// K2: x (NCHW fp32) -> t (b, y', x', c) bf16 with zeroed 1-px halo border.
// Mean fused as PARTIAL sums: y0p[b][y][c] (no atomics, no memset needed).
__global__ void k_tr(const float* __restrict__ x, unsigned short* __restrict__ t,
                     float* __restrict__ y0p) {
    int blk = blockIdx.x;
    int b = blk >> 7, y = blk & 127;
    __shared__ unsigned short lds[C_ * TW];
    int tid = threadIdx.x;
    for (int i = tid; i < C_ * 32; i += 256) {
        int c = i >> 5, xq = i & 31;
        float4 v = *(const float4*)(x + (((size_t)(b * C_ + c)) << 14) + (y << 7) + (xq << 2));
        unsigned int p0 = f2us(v.x) | ((unsigned int)f2us(v.y) << 16);
        unsigned int p1 = f2us(v.z) | ((unsigned int)f2us(v.w) << 16);
        *(unsigned int*)&lds[c * TW + (xq << 2)]     = p0;
        *(unsigned int*)&lds[c * TW + (xq << 2) + 2] = p1;
        float s4 = v.x + v.y + v.z + v.w;
        s4 += __shfl_down(s4, 16, 32);
        s4 += __shfl_down(s4, 8, 32);
        s4 += __shfl_down(s4, 4, 32);
        s4 += __shfl_down(s4, 2, 32);
        s4 += __shfl_down(s4, 1, 32);
        if ((tid & 31) == 0) y0p[(((b << 7) + y) << 6) + c] = s4;
    }
    __syncthreads();
    size_t rowbase = ((size_t)(b * TW + y + 1)) * TW * C_;
    for (int j = tid; j < 128 * 16; j += 256) {
        int px = j >> 4, g = j & 15;
        unsigned short a0 = lds[(4 * g + 0) * TW + px];
        unsigned short a1 = lds[(4 * g + 1) * TW + px];
        unsigned short a2 = lds[(4 * g + 2) * TW + px];
        unsigned short a3 = lds[(4 * g + 3) * TW + px];
        uint2 wv;
        wv.x = a0 | ((unsigned int)a1 << 16);
        wv.y = a2 | ((unsigned int)a3 << 16);
        *(uint2*)(t + rowbase + (size_t)(px + 1) * C_ + (g << 2)) = wv;
    }
    if (tid < 16) {
        int px = (tid < 8) ? 0 : (TW - 1);
        int ch = tid & 7;
        uint4 z = {0, 0, 0, 0};
        *(uint4*)(t + rowbase + (size_t)px * C_ + ch * 8) = z;
    }
    if (y == 0) {
        size_t base = (size_t)b * TW * TW * C_;
        uint4 z = {0, 0, 0, 0};
        for (int i = tid; i < TW * C_ / 8; i += 256)
            *(uint4*)(t + base + (size_t)i * 8) = z;
    }
    if (y == 127) {
        size_t base = ((size_t)(b * TW + TW - 1)) * TW * C_;
        uint4 z = {0, 0, 0, 0};
        for (int i = tid; i < TW * C_ / 8; i += 256)
            *(uint4*)(t + base + (size_t)i * 8) = z;
    }
}

// ---------------------------------------------------------------------------
// K4: fused channel attention + w_t build (MFMA-fragment-ordered) + w1t
// transpose (block 0). Reduces y0p partials (replaces the old atomic y0).
// grid = B*4.
__global__ void k_attwt(const float* __restrict__ y0p,
                        const float* __restrict__ fc_w1,
                        const float* __restrict__ fc_w2,
                        const float* __restrict__ weight,
                        const float* __restrict__ se_w1,
                        unsigned short* __restrict__ w_t,
                        unsigned short* __restrict__ w1t) {
    int blk = blockIdx.x;
    int b = blk >> 2, mt = blk & 3;
    __shared__ float sy0[C_];
    __shared__ float sh[CR_];
    __shared__ float ssy[K9C];
    __shared__ float sw[16 * 576];
    int tid = threadIdx.x;
    if (blk == 0) {
        for (int i = tid; i < 9 * 16 * C_; i += 256) {
            int tap = i >> 10, o = (i >> 6) & 15, c = i & 63;
            w1t[i] = f2us(se_w1[(o * C_ + c) * 9 + tap]);
        }
    }
    if (tid < C_) {
        float s = 0.f;
        const float* pp = y0p + ((size_t)b << 13) + tid;
        for (int y = 0; y < 128; ++y) s += pp[y << 6];
        sy0[tid] = s * (1.0f / (float)HW_);
    }
    const float* wsrc = weight + (size_t)(mt * 16) * 576;
    for (int i = tid; i < 16 * 576; i += 256) sw[i] = wsrc[i];
    __syncthreads();
    if (tid < CR_) {
        float s = 0.f;
        for (int c = 0; c < C_; ++c) s = fmaf(fc_w1[tid * C_ + c], sy0[c], s);
        sh[tid] = fmaxf(s, 0.f);
    }
    __syncthreads();
    for (int i = tid; i < K9C; i += 256) {
        float s = 0.f;
        #pragma unroll
        for (int j = 0; j < CR_; ++j) s = fmaf(fc_w2[i * CR_ + j], sh[j], s);
        ssy[i] = 1.f / (1.f + expf(-s));
    }
    __syncthreads();
    unsigned short* wb = w_t + (size_t)b * 9 * C_ * C_;
    for (int ii = tid; ii < 4608; ii += 256) {
        int i = ii << 1;
        int tap = i >> 10, r = i & 1023;
        int half = r >> 9, lane = (r >> 3) & 63, e = r & 7;
        int o = lane & 15;
        int c = half * 32 + ((lane >> 4) << 3) + e;
        float v0 = sw[o * 576 + c * 9 + tap] * ssy[c * 9 + tap];
        float v1 = sw[o * 576 + (c + 1) * 9 + tap] * ssy[(c + 1) * 9 + tap];
        unsigned int pk = f2us(v0) | ((unsigned int)f2us(v1) << 16);
        *(unsigned int*)(wb + ((tap * 4 + mt) * 2 + half) * 512 + lane * 8 + e) = pk;
    }
}

// ---------------------------------------------------------------------------
// K5: FULLY FUSED main+SE.
// Round-8 changes:
//  - x-stage via global_load_lds: linear LDS dest, PRE-SWIZZLED per-lane
//    global source (rule: swizzle both-sides-or-neither). Deletes the staged
//    VGPR round-trip + 55KB of ds_writes; 7 DMA issues drained by one barrier.
//  - single-pass epilogue: both j2 through one 72KB fb (2 barriers, was 4).
//  - setprio around conv1's MFMA cluster.
__global__ void __launch_bounds__(512, 4)
k_fused(const unsigned short* __restrict__ t, const unsigned short* __restrict__ w_t,
        const unsigned short* __restrict__ w1t, const float* __restrict__ se_w2,
        float* __restrict__ out) {
    int blk = swz64(blockIdx.x);
    int b = blk >> 6, tile = blk & 63;
    int ty0 = (tile >> 2) << 3, tx0 = (tile & 3) << 5;
    int tid = threadIdx.x, lane = tid & 63, wave = tid >> 6;
    int wy = wave >> 1, wx = wave & 1;
    int n = lane & 15, q = lane >> 4, qc = q << 3;
    __shared__ __align__(16) char smem[LDSZ];
    float* fb  = (float*)smem;                 // epilogue reuse [512][FBS] = 72KB
    float* mid = (float*)(smem + MIDOFF);      // [340 px][MIDS] (after main conv)
    float* w2l = (float*)(smem + W2OFF);       // [9 tap][16 ch]

    // ---- stage 12x36 pixel tile via DMA: LDS slot s holds chunk ch^(px&7)
    // of pixel (row,px); read path applies the same XOR -> consistent. ----
    const unsigned short* tbb = t + (size_t)b * TW * TW * C_;
    #pragma unroll
    for (int it = 0; it < 7; ++it) {
        int s = (it << 9) + tid;
        if (s < STG_H * STG_W * 8) {           // wave-uniform (3456 = 54 waves)
            int row = s / 288, r = s % 288, px = r >> 3, chp = r & 7;
            int tr = ty0 - 1 + row; tr = tr < 0 ? 0 : (tr > TW - 1 ? TW - 1 : tr);
            int tc = tx0 - 1 + px;  tc = tc < 0 ? 0 : (tc > TW - 1 ? TW - 1 : tc);
            int ch = chp ^ (px & 7);
            __builtin_amdgcn_global_load_lds(
                (const __attribute__((address_space(1))) void*)(tbb + ((size_t)tr * TW + tc) * C_ + (ch << 3)),
                (__attribute__((address_space(3))) void*)(smem + (s << 4)), 16, 0, 0);
        }
    }
    if (tid < 144) w2l[tid] = se_w2[(tid & 15) * 9 + (tid >> 4)];

    // ---- main conv; w_t triple-buffered through LDS, counted-vmcnt drain ----
    const unsigned short* wb = w_t + (size_t)b * 9 * C_ * C_;
    #define STAGE_WT(tp) \
        __builtin_amdgcn_global_load_lds( \
            (const __attribute__((address_space(1))) void*)(wb + (tp) * 4096 + (wave << 9) + (lane << 3)), \
            (__attribute__((address_space(3))) void*)(smem + MIDOFF + ((tp) % 3) * WTB + (wave << 10)), \
            16, 0, 0)
    STAGE_WT(0);
    STAGE_WT(1);
    __syncthreads();   // x-stage DMA + w2l + stages 0,1 fully drained

    f32x4 acc[4][2] = {};
    #pragma unroll
    for (int tap = 0; tap < 9; ++tap) {
        if (tap) {
            // own slice of stage(tap) landed: keep at most 1 newer in flight
            if (tap < 8) asm volatile("s_waitcnt vmcnt(1)" ::: "memory");
            else         asm volatile("s_waitcnt vmcnt(0)" ::: "memory");
            __builtin_amdgcn_s_barrier();              // all waves' slices landed
            __builtin_amdgcn_sched_barrier(0);         // no hoisting past barrier
        }
        if (tap < 7) STAGE_WT(tap + 2);   // overwrites buf read at tap-1 (safe)
        int ki = tap / 3, kj = tap % 3;
        int xl = (wx << 4) + n + kj + 1;
        int xk = xl & 7;
        const char* tapbuf = smem + MIDOFF + (tap % 3) * WTB;
        __builtin_amdgcn_s_setprio(1);
        #pragma unroll
        for (int half = 0; half < 2; ++half) {
            bf16x8 af[4];
            #pragma unroll
            for (int mt = 0; mt < 4; ++mt) {
                uint4 au = *(const uint4*)(tapbuf + (((mt << 1) + half) << 10) + (lane << 4));
                af[mt] = __builtin_bit_cast(bf16x8, au);
            }
            int slot = (((half << 2) + q) ^ xk) << 4;
            #pragma unroll
            for (int j2 = 0; j2 < 2; ++j2) {
                int yl = (wy << 1) + j2 + ki + 1;
                bf16x8 bf = *(const bf16x8*)(smem + (yl * STG_W + xl) * 128 + slot);
                #pragma unroll
                for (int mt = 0; mt < 4; ++mt)
                    acc[mt][j2] = __builtin_amdgcn_mfma_f32_16x16x32_bf16(af[mt], bf, acc[mt][j2], 0, 0, 0);
            }
        }
        __builtin_amdgcn_s_setprio(0);
    }
    #undef STAGE_WT
    __syncthreads();   // all buf reads done; region becomes mid

    // ---- conv1 -> mid (relu + border mask), tap-outer (w1t loaded 18x) ----
    int mr[3], mc[3], pp[3];
    bool on[3];
    #pragma unroll
    for (int i = 0; i < 3; ++i) {
        int g = wave + (i << 3);
        on[i] = (g < 22);
        int p = g * 16 + n; if (p > 339) p = 339;
        pp[i] = p; mr[i] = p / 34; mc[i] = p - mr[i] * 34;
    }
    f32x4 a1_0 = {}, a1_1 = {}, a1_2 = {};
    __builtin_amdgcn_s_setprio(1);
    #pragma unroll
    for (int tap = 0; tap < 9; ++tap) {
        int ki = tap / 3, kj = tap % 3;
        uint4 u0 = *(const uint4*)(w1t + (tap * 16 + n) * C_ + qc);
        uint4 u1 = *(const uint4*)(w1t + (tap * 16 + n) * C_ + 32 + qc);
        bf16x8 af0 = __builtin_bit_cast(bf16x8, u0);
        bf16x8 af1 = __builtin_bit_cast(bf16x8, u1);
        #pragma unroll
        for (int i = 0; i < 3; ++i) {
            if (on[i]) {
                int sc = mc[i] + kj;
                int sb = ((mr[i] + ki) * STG_W + sc) * 128;
                bf16x8 b0 = *(const bf16x8*)(smem + sb + ((q ^ (sc & 7)) << 4));
                bf16x8 b1 = *(const bf16x8*)(smem + sb + (((4 + q) ^ (sc & 7)) << 4));
                f32x4 t0 = (i == 0) ? a1_0 : (i == 1) ? a1_1 : a1_2;
                t0 = __builtin_amdgcn_mfma_f32_16x16x32_bf16(af0, b0, t0, 0, 0, 0);
                t0 = __builtin_amdgcn_mfma_f32_16x16x32_bf16(af1, b1, t0, 0, 0, 0);
                if (i == 0) a1_0 = t0; else if (i == 1) a1_1 = t0; else a1_2 = t0;
            }
        }
    }
    __builtin_amdgcn_s_setprio(0);
    #pragma unroll
    for (int i = 0; i < 3; ++i) {
        int g = wave + (i << 3);
        if (on[i] && (g < 21 || n < 4)) {   // skip duplicate lanes of group 21
            int my = ty0 - 1 + mr[i], mx = tx0 - 1 + mc[i];
            bool valid = (my >= 0) && (my < 128) && (mx >= 0) && (mx < 128);
            f32x4 av = (i == 0) ? a1_0 : (i == 1) ? a1_1 : a1_2;
            #pragma unroll
            for (int r = 0; r < 4; ++r)
                mid[pp[i] * MIDS + (q << 2) + r] = valid ? fmaxf(av[r], 0.f) : 0.f;
        }
    }
    __syncthreads();   // mid visible

    // ---- conv2 + sigmoid -> A in registers (q-split channels + shfl reduce) ----
    float4 wq[9];
    #pragma unroll
    for (int tap = 0; tap < 9; ++tap)
        wq[tap] = *(const float4*)&w2l[tap * 16 + (q << 2)];
    float Av[2];
    #pragma unroll
    for (int j2 = 0; j2 < 2; ++j2) {
        float s = 0.f;
        #pragma unroll
        for (int di = 0; di < 3; ++di) {
            #pragma unroll
            for (int dj = 0; dj < 3; ++dj) {
                int p = ((wy << 1) + j2 + di) * 34 + (wx << 4) + n + dj;
                const float* mp = &mid[p * MIDS + (q << 2)];
                float2 m0 = *(const float2*)mp;
                float2 m1 = *(const float2*)(mp + 2);
                float4 wv = wq[di * 3 + dj];
                s = fmaf(m0.x, wv.x, s);
                s = fmaf(m0.y, wv.y, s);
                s = fmaf(m1.x, wv.z, s);
                s = fmaf(m1.y, wv.w, s);
            }
        }
        s += __shfl_xor(s, 16, 64);
        s += __shfl_xor(s, 32, 64);
        Av[j2] = 1.f / (1.f + expf(-s));
    }

    // ---- epilogue (single pass): A-scale -> 72KB fb -> full-line stores ----
    __syncthreads();   // conv2's mid reads done; fb may overwrite everything
    #pragma unroll
    for (int j2 = 0; j2 < 2; ++j2) {
        #pragma unroll
        for (int mt = 0; mt < 4; ++mt) {
            #pragma unroll
            for (int r = 0; r < 4; ++r) {
                int o = (mt << 4) + (q << 2) + r;
                fb[((j2 << 8) + (wy << 6) + o) * FBS + (wx << 4) + n] = acc[mt][j2][r] * Av[j2];
            }
        }
    }
    __syncthreads();
    #pragma unroll
    for (int it = 0; it < 8; ++it) {
        int s = it * 512 + tid;
        int row = s >> 3, xq = s & 7;
        int j2 = row >> 8, rr = row & 255;
        int wy2 = rr >> 6, o = rr & 63;
        float4 v = *(const float4*)&fb[row * FBS + (xq << 2)];
        *(float4*)(out + (((size_t)(b * C_ + o)) << 14) +
                   ((ty0 + (wy2 << 1) + j2) << 7) + tx0 + (xq << 2)) = v;
    }
}

// ---------------------------------------------------------------------------
extern "C" void kernel_launch(void* const* d_in, const int* in_sizes, int n_in,
                              void* d_out, int out_size, void* d_ws, size_t ws_size,
                              hipStream_t stream) {
    const float* x      = (const float*)d_in[0];
    const float* weight = (const float*)d_in[1];
    const float* se_w1  = (const float*)d_in[2];
    const float* se_w2  = (const float*)d_in[3];
    const float* fc_w1  = (const float*)d_in[4];
    const float* fc_w2  = (const float*)d_in[5];
    float* out = (float*)d_out;

    char* ws = (char*)d_ws;
    float* y0p           = (float*)ws;                         ws += (size_t)B_ * H_ * C_ * 4;
    unsigned short* t    = (unsigned short*)ws;                ws += (size_t)B_ * TW * TW * C_ * 2 + 4096;
    unsigned short* w_t  = (unsigned short*)ws;                ws += (size_t)B_ * 9 * C_ * C_ * 2;
    unsigned short* w1t  = (unsigned short*)ws;

    k_tr   <<<B_ * H_, 256, 0, stream>>>(x, t, y0p);          // + partial means
    k_attwt<<<B_ * 4, 256, 0, stream>>>(y0p, fc_w1, fc_w2, weight, se_w1, w_t, w1t);
    k_fused<<<B_ * 64, 512, 0, stream>>>(t, w_t, w1t, se_w2, out);
}

// Round 9
// 169.190 us; speedup vs baseline: 1.4908x; 1.0362x over previous
//
#include <hip/hip_runtime.h>
#include <hip/hip_bf16.h>
#include <math.h>

#define B_  16
#define C_  64
#define H_  128
#define W_  128
#define HW_ (H_ * W_)
#define CR_ 4
#define K9C (9 * C_)   // 576
#define TW  130        // transposed buffer spatial dim (128 + 2 halo)
#define FBS 36         // epilogue fb row stride (floats)
#define STG_W 36       // staged tile: 12 rows x 36 cols of pixels (128B each)
#define STG_H 12
#define MIDOFF (STG_H * STG_W * 128)        // 55296; w_t triple-buf, later mid
#define MIDS 18                             // mid pixel stride (floats)
#define WTB 8192                            // one tap of w_t in LDS
#define W2OFF (MIDOFF + 3 * WTB)            // 79872
#define LDSZ  (W2OFF + 144 * 4)             // 80448 (<= 81920: 2 blocks/CU)

typedef float f32x4 __attribute__((ext_vector_type(4)));
typedef __bf16 bf16x8 __attribute__((ext_vector_type(8)));

static __device__ __forceinline__ unsigned short f2us(float f) {
    __bf16 h = (__bf16)f;
    return __builtin_bit_cast(unsigned short, h);
}

// XCD-aware bijective swizzle: grid 1024 = 16 batches x 64 tiles; each XCD
// walks whole batches (per-XCD L2 working set = one batch's t = 2.16 MB).
static __device__ __forceinline__ int swz64(int blk) {
    int xcd = blk & 7, i = blk >> 3;
    return ((i >> 6) << 9) + (xcd << 6) + (i & 63);
}

// ---------------------------------------------------------------------------
// K2: x (NCHW fp32) -> t (b, y', x', c) bf16 with zeroed 1-px halo border.
// Round-9 rewrite: thread owns a fixed CHANNEL-PAIR (c, c+1) for all its
// pixels -> mean costs 3 width-8 shuffles per channel (was 40 bpermutes);
// LDS transpose via u32 channel-pairs, ds_write_b64 into XOR layout
// [cpair][px ^ ((cpair&15)<<1)] (4-way writes, 2-way=free reads), phase-2
// reads 2x ds_read_b32 (was 4x ds_read_u16). Mean stored as partials y0p.
__global__ void k_tr(const float* __restrict__ x, unsigned short* __restrict__ t,
                     float* __restrict__ y0p) {
    int blk = blockIdx.x;
    int b = blk >> 7, y = blk & 127;
    __shared__ unsigned int lds2[32 * 128];   // [cpair][col], col = px ^ F(cpair)
    int tid = threadIdx.x;
    int cpair = tid >> 3, q8 = tid & 7;
    int F = (cpair & 15) << 1;
    const float* x0 = x + (((size_t)(b * C_ + (cpair << 1))) << 14) + (y << 7);
    float s0 = 0.f, s1 = 0.f;
    #pragma unroll
    for (int k = 0; k < 4; ++k) {
        int px0 = (q8 + (k << 3)) << 2;
        float4 v0 = *(const float4*)(x0 + px0);
        float4 v1 = *(const float4*)(x0 + 16384 + px0);
        s0 += v0.x + v0.y + v0.z + v0.w;
        s1 += v1.x + v1.y + v1.z + v1.w;
        uint2 a, c;
        a.x = f2us(v0.x) | ((unsigned int)f2us(v1.x) << 16);
        a.y = f2us(v0.y) | ((unsigned int)f2us(v1.y) << 16);
        c.x = f2us(v0.z) | ((unsigned int)f2us(v1.z) << 16);
        c.y = f2us(v0.w) | ((unsigned int)f2us(v1.w) << 16);
        *(uint2*)&lds2[(cpair << 7) + (px0 ^ F)] = a;
        *(uint2*)&lds2[(cpair << 7) + ((px0 + 2) ^ F)] = c;
    }
    // mean partials: reduce across the 8 lanes sharing this channel-pair
    s0 += __shfl_down(s0, 4, 8); s0 += __shfl_down(s0, 2, 8); s0 += __shfl_down(s0, 1, 8);
    s1 += __shfl_down(s1, 4, 8); s1 += __shfl_down(s1, 2, 8); s1 += __shfl_down(s1, 1, 8);
    if (q8 == 0) {
        float2 m = {s0, s1};
        *(float2*)&y0p[(((b << 7) + y) << 6) + (cpair << 1)] = m;
    }
    __syncthreads();
    // phase 2: 16 lanes per px -> one full 128B line per write group
    size_t rowbase = ((size_t)(b * TW + y + 1)) * TW * C_;
    #pragma unroll
    for (int k = 0; k < 8; ++k) {
        int j = tid + (k << 8);
        int px = j >> 4, gq = j & 15;
        int r0 = gq << 1, r1 = r0 + 1;
        uint2 wv;
        wv.x = lds2[(r0 << 7) + (px ^ ((r0 & 15) << 1))];
        wv.y = lds2[(r1 << 7) + (px ^ ((r1 & 15) << 1))];
        *(uint2*)(t + rowbase + (size_t)(px + 1) * C_ + (gq << 2)) = wv;
    }
    if (tid < 16) {
        int px = (tid < 8) ? 0 : (TW - 1);
        int ch = tid & 7;
        uint4 z = {0, 0, 0, 0};
        *(uint4*)(t + rowbase + (size_t)px * C_ + ch * 8) = z;
    }
    if (y == 0) {
        size_t base = (size_t)b * TW * TW * C_;
        uint4 z = {0, 0, 0, 0};
        for (int i = tid; i < TW * C_ / 8; i += 256)
            *(uint4*)(t + base + (size_t)i * 8) = z;
    }
    if (y == 127) {
        size_t base = ((size_t)(b * TW + TW - 1)) * TW * C_;
        uint4 z = {0, 0, 0, 0};
        for (int i = tid; i < TW * C_ / 8; i += 256)
            *(uint4*)(t + base + (size_t)i * 8) = z;
    }
}

// ---------------------------------------------------------------------------
// K4: fused channel attention + w_t build + w1t transpose.
// Round-9: grid 64 -> 256 blocks (b, mt, quarter-slice of taps); all 256
// threads do the y0p reduction (coalesced); w1t spread over 9 blocks.
__global__ void k_attwt(const float* __restrict__ y0p,
                        const float* __restrict__ fc_w1,
                        const float* __restrict__ fc_w2,
                        const float* __restrict__ weight,
                        const float* __restrict__ se_w1,
                        unsigned short* __restrict__ w_t,
                        unsigned short* __restrict__ w1t) {
    int blk = blockIdx.x;
    int b = blk >> 4, part = blk & 15, mt = part >> 2, hk = part & 3;
    __shared__ float red[256];
    __shared__ float sy0[C_];
    __shared__ float sh[CR_];
    __shared__ float ssy[K9C];
    __shared__ float sw[16 * 576];
    int tid = threadIdx.x;
    // w1t: 9 of the b==0 blocks each handle one tap
    if (b == 0 && part < 9) {
        int tap = part;
        for (int j = tid; j < 1024; j += 256)
            w1t[tap * 1024 + j] = f2us(se_w1[j * 9 + tap]);
    }
    // y0p reduce: c = tid&63, y-quarter = tid>>6 (coalesced 256B rows)
    {
        float s = 0.f;
        const float* pp = y0p + ((size_t)b << 13) + ((tid >> 6) << 11) + (tid & 63);
        #pragma unroll
        for (int yy = 0; yy < 32; ++yy) s += pp[yy << 6];
        red[tid] = s;
    }
    const float* wsrc = weight + (size_t)(mt * 16) * 576;
    for (int i = tid; i < 16 * 576; i += 256) sw[i] = wsrc[i];
    __syncthreads();
    if (tid < C_)
        sy0[tid] = (red[tid] + red[tid + 64] + red[tid + 128] + red[tid + 192])
                   * (1.0f / (float)HW_);
    __syncthreads();
    if (tid < CR_) {
        float s = 0.f;
        for (int c = 0; c < C_; ++c) s = fmaf(fc_w1[tid * C_ + c], sy0[c], s);
        sh[tid] = fmaxf(s, 0.f);
    }
    __syncthreads();
    for (int i = tid; i < K9C; i += 256) {
        float s = 0.f;
        #pragma unroll
        for (int j = 0; j < CR_; ++j) s = fmaf(fc_w2[i * CR_ + j], sh[j], s);
        ssy[i] = 1.f / (1.f + expf(-s));
    }
    __syncthreads();
    unsigned short* wb = w_t + (size_t)b * 9 * C_ * C_;
    for (int ii = hk * 1152 + tid; ii < (hk + 1) * 1152; ii += 256) {
        int i = ii << 1;
        int tap = i >> 10, r = i & 1023;
        int half = r >> 9, lane = (r >> 3) & 63, e = r & 7;
        int o = lane & 15;
        int c = half * 32 + ((lane >> 4) << 3) + e;
        float v0 = sw[o * 576 + c * 9 + tap] * ssy[c * 9 + tap];
        float v1 = sw[o * 576 + (c + 1) * 9 + tap] * ssy[(c + 1) * 9 + tap];
        unsigned int pk = f2us(v0) | ((unsigned int)f2us(v1) << 16);
        *(unsigned int*)(wb + ((tap * 4 + mt) * 2 + half) * 512 + lane * 8 + e) = pk;
    }
}

// ---------------------------------------------------------------------------
// K5: FULLY FUSED main+SE (unchanged from round 8).
__global__ void __launch_bounds__(512, 4)
k_fused(const unsigned short* __restrict__ t, const unsigned short* __restrict__ w_t,
        const unsigned short* __restrict__ w1t, const float* __restrict__ se_w2,
        float* __restrict__ out) {
    int blk = swz64(blockIdx.x);
    int b = blk >> 6, tile = blk & 63;
    int ty0 = (tile >> 2) << 3, tx0 = (tile & 3) << 5;
    int tid = threadIdx.x, lane = tid & 63, wave = tid >> 6;
    int wy = wave >> 1, wx = wave & 1;
    int n = lane & 15, q = lane >> 4, qc = q << 3;
    __shared__ __align__(16) char smem[LDSZ];
    float* fb  = (float*)smem;                 // epilogue reuse [512][FBS] = 72KB
    float* mid = (float*)(smem + MIDOFF);      // [340 px][MIDS] (after main conv)
    float* w2l = (float*)(smem + W2OFF);       // [9 tap][16 ch]

    // ---- stage 12x36 pixel tile via DMA: LDS slot s holds chunk ch^(px&7)
    // of pixel (row,px); read path applies the same XOR -> consistent. ----
    const unsigned short* tbb = t + (size_t)b * TW * TW * C_;
    #pragma unroll
    for (int it = 0; it < 7; ++it) {
        int s = (it << 9) + tid;
        if (s < STG_H * STG_W * 8) {           // wave-uniform (3456 = 54 waves)
            int row = s / 288, r = s % 288, px = r >> 3, chp = r & 7;
            int tr = ty0 - 1 + row; tr = tr < 0 ? 0 : (tr > TW - 1 ? TW - 1 : tr);
            int tc = tx0 - 1 + px;  tc = tc < 0 ? 0 : (tc > TW - 1 ? TW - 1 : tc);
            int ch = chp ^ (px & 7);
            __builtin_amdgcn_global_load_lds(
                (const __attribute__((address_space(1))) void*)(tbb + ((size_t)tr * TW + tc) * C_ + (ch << 3)),
                (__attribute__((address_space(3))) void*)(smem + (s << 4)), 16, 0, 0);
        }
    }
    if (tid < 144) w2l[tid] = se_w2[(tid & 15) * 9 + (tid >> 4)];

    // ---- main conv; w_t triple-buffered through LDS, counted-vmcnt drain ----
    const unsigned short* wb = w_t + (size_t)b * 9 * C_ * C_;
    #define STAGE_WT(tp) \
        __builtin_amdgcn_global_load_lds( \
            (const __attribute__((address_space(1))) void*)(wb + (tp) * 4096 + (wave << 9) + (lane << 3)), \
            (__attribute__((address_space(3))) void*)(smem + MIDOFF + ((tp) % 3) * WTB + (wave << 10)), \
            16, 0, 0)
    STAGE_WT(0);
    STAGE_WT(1);
    __syncthreads();   // x-stage DMA + w2l + stages 0,1 fully drained

    f32x4 acc[4][2] = {};
    #pragma unroll
    for (int tap = 0; tap < 9; ++tap) {
        if (tap) {
            // own slice of stage(tap) landed: keep at most 1 newer in flight
            if (tap < 8) asm volatile("s_waitcnt vmcnt(1)" ::: "memory");
            else         asm volatile("s_waitcnt vmcnt(0)" ::: "memory");
            __builtin_amdgcn_s_barrier();              // all waves' slices landed
            __builtin_amdgcn_sched_barrier(0);         // no hoisting past barrier
        }
        if (tap < 7) STAGE_WT(tap + 2);   // overwrites buf read at tap-1 (safe)
        int ki = tap / 3, kj = tap % 3;
        int xl = (wx << 4) + n + kj + 1;
        int xk = xl & 7;
        const char* tapbuf = smem + MIDOFF + (tap % 3) * WTB;
        __builtin_amdgcn_s_setprio(1);
        #pragma unroll
        for (int half = 0; half < 2; ++half) {
            bf16x8 af[4];
            #pragma unroll
            for (int mt = 0; mt < 4; ++mt) {
                uint4 au = *(const uint4*)(tapbuf + (((mt << 1) + half) << 10) + (lane << 4));
                af[mt] = __builtin_bit_cast(bf16x8, au);
            }
            int slot = (((half << 2) + q) ^ xk) << 4;
            #pragma unroll
            for (int j2 = 0; j2 < 2; ++j2) {
                int yl = (wy << 1) + j2 + ki + 1;
                bf16x8 bf = *(const bf16x8*)(smem + (yl * STG_W + xl) * 128 + slot);
                #pragma unroll
                for (int mt = 0; mt < 4; ++mt)
                    acc[mt][j2] = __builtin_amdgcn_mfma_f32_16x16x32_bf16(af[mt], bf, acc[mt][j2], 0, 0, 0);
            }
        }
        __builtin_amdgcn_s_setprio(0);
    }
    #undef STAGE_WT
    __syncthreads();   // all buf reads done; region becomes mid

    // ---- conv1 -> mid (relu + border mask), tap-outer (w1t loaded 18x) ----
    int mr[3], mc[3], pp[3];
    bool on[3];
    #pragma unroll
    for (int i = 0; i < 3; ++i) {
        int g = wave + (i << 3);
        on[i] = (g < 22);
        int p = g * 16 + n; if (p > 339) p = 339;
        pp[i] = p; mr[i] = p / 34; mc[i] = p - mr[i] * 34;
    }
    f32x4 a1_0 = {}, a1_1 = {}, a1_2 = {};
    __builtin_amdgcn_s_setprio(1);
    #pragma unroll
    for (int tap = 0; tap < 9; ++tap) {
        int ki = tap / 3, kj = tap % 3;
        uint4 u0 = *(const uint4*)(w1t + (tap * 16 + n) * C_ + qc);
        uint4 u1 = *(const uint4*)(w1t + (tap * 16 + n) * C_ + 32 + qc);
        bf16x8 af0 = __builtin_bit_cast(bf16x8, u0);
        bf16x8 af1 = __builtin_bit_cast(bf16x8, u1);
        #pragma unroll
        for (int i = 0; i < 3; ++i) {
            if (on[i]) {
                int sc = mc[i] + kj;
                int sb = ((mr[i] + ki) * STG_W + sc) * 128;
                bf16x8 b0 = *(const bf16x8*)(smem + sb + ((q ^ (sc & 7)) << 4));
                bf16x8 b1 = *(const bf16x8*)(smem + sb + (((4 + q) ^ (sc & 7)) << 4));
                f32x4 t0 = (i == 0) ? a1_0 : (i == 1) ? a1_1 : a1_2;
                t0 = __builtin_amdgcn_mfma_f32_16x16x32_bf16(af0, b0, t0, 0, 0, 0);
                t0 = __builtin_amdgcn_mfma_f32_16x16x32_bf16(af1, b1, t0, 0, 0, 0);
                if (i == 0) a1_0 = t0; else if (i == 1) a1_1 = t0; else a1_2 = t0;
            }
        }
    }
    __builtin_amdgcn_s_setprio(0);
    #pragma unroll
    for (int i = 0; i < 3; ++i) {
        int g = wave + (i << 3);
        if (on[i] && (g < 21 || n < 4)) {   // skip duplicate lanes of group 21
            int my = ty0 - 1 + mr[i], mx = tx0 - 1 + mc[i];
            bool valid = (my >= 0) && (my < 128) && (mx >= 0) && (mx < 128);
            f32x4 av = (i == 0) ? a1_0 : (i == 1) ? a1_1 : a1_2;
            #pragma unroll
            for (int r = 0; r < 4; ++r)
                mid[pp[i] * MIDS + (q << 2) + r] = valid ? fmaxf(av[r], 0.f) : 0.f;
        }
    }
    __syncthreads();   // mid visible

    // ---- conv2 + sigmoid -> A in registers (q-split channels + shfl reduce) ----
    float4 wq[9];
    #pragma unroll
    for (int tap = 0; tap < 9; ++tap)
        wq[tap] = *(const float4*)&w2l[tap * 16 + (q << 2)];
    float Av[2];
    #pragma unroll
    for (int j2 = 0; j2 < 2; ++j2) {
        float s = 0.f;
        #pragma unroll
        for (int di = 0; di < 3; ++di) {
            #pragma unroll
            for (int dj = 0; dj < 3; ++dj) {
                int p = ((wy << 1) + j2 + di) * 34 + (wx << 4) + n + dj;
                const float* mp = &mid[p * MIDS + (q << 2)];
                float2 m0 = *(const float2*)mp;
                float2 m1 = *(const float2*)(mp + 2);
                float4 wv = wq[di * 3 + dj];
                s = fmaf(m0.x, wv.x, s);
                s = fmaf(m0.y, wv.y, s);
                s = fmaf(m1.x, wv.z, s);
                s = fmaf(m1.y, wv.w, s);
            }
        }
        s += __shfl_xor(s, 16, 64);
        s += __shfl_xor(s, 32, 64);
        Av[j2] = 1.f / (1.f + expf(-s));
    }

    // ---- epilogue (single pass): A-scale -> 72KB fb -> full-line stores ----
    __syncthreads();   // conv2's mid reads done; fb may overwrite everything
    #pragma unroll
    for (int j2 = 0; j2 < 2; ++j2) {
        #pragma unroll
        for (int mt = 0; mt < 4; ++mt) {
            #pragma unroll
            for (int r = 0; r < 4; ++r) {
                int o = (mt << 4) + (q << 2) + r;
                fb[((j2 << 8) + (wy << 6) + o) * FBS + (wx << 4) + n] = acc[mt][j2][r] * Av[j2];
            }
        }
    }
    __syncthreads();
    #pragma unroll
    for (int it = 0; it < 8; ++it) {
        int s = it * 512 + tid;
        int row = s >> 3, xq = s & 7;
        int j2 = row >> 8, rr = row & 255;
        int wy2 = rr >> 6, o = rr & 63;
        float4 v = *(const float4*)&fb[row * FBS + (xq << 2)];
        *(float4*)(out + (((size_t)(b * C_ + o)) << 14) +
                   ((ty0 + (wy2 << 1) + j2) << 7) + tx0 + (xq << 2)) = v;
    }
}

// ---------------------------------------------------------------------------
extern "C" void kernel_launch(void* const* d_in, const int* in_sizes, int n_in,
                              void* d_out, int out_size, void* d_ws, size_t ws_size,
                              hipStream_t stream) {
    const float* x      = (const float*)d_in[0];
    const float* weight = (const float*)d_in[1];
    const float* se_w1  = (const float*)d_in[2];
    const float* se_w2  = (const float*)d_in[3];
    const float* fc_w1  = (const float*)d_in[4];
    const float* fc_w2  = (const float*)d_in[5];
    float* out = (float*)d_out;

    char* ws = (char*)d_ws;
    float* y0p           = (float*)ws;                         ws += (size_t)B_ * H_ * C_ * 4;
    unsigned short* t    = (unsigned short*)ws;                ws += (size_t)B_ * TW * TW * C_ * 2 + 4096;
    unsigned short* w_t  = (unsigned short*)ws;                ws += (size_t)B_ * 9 * C_ * C_ * 2;
    unsigned short* w1t  = (unsigned short*)ws;

    k_tr   <<<B_ * H_, 256, 0, stream>>>(x, t, y0p);          // + partial means
    k_attwt<<<B_ * 16, 256, 0, stream>>>(y0p, fc_w1, fc_w2, weight, se_w1, w_t, w1t);
    k_fused<<<B_ * 64, 512, 0, stream>>>(t, w_t, w1t, se_w2, out);
}